// Round 11
// baseline (1021.422 us; speedup 1.0000x reference)
//
#include <hip/hip_runtime.h>
#include <cstddef>
#include <cstdint>

// Problem constants (fixed by setup_inputs)
#define E_EDGES 131072
#define N_NODES 8192
#define D_INF   192
#define L_DIM   256
#define OUT_D   416
#define EPS6    1e-6f
#define GA      40            // LDS row stride (shorts) for gemm_wide tiles

// ws layout (float offsets)
#define WS_HHI   0ull          // E*256 bf16 hi plane (G1/G3 out)
#define WS_HLO   16777216ull   // E*256 bf16 lo plane
#define WS_ATT   33554432ull   // E*32 f32 logits
#define WS_ENV2  37748736ull   // N*128 f32
#define WS_CNT   38797312ull   // N int
#define WS_ROWPTR 38805504ull  // N+1 int (padded)
#define WS_CURSOR 38813760ull  // N int
#define WS_EIDX  38821952ull   // E int
#define WS_WB    38953024ull   // bf16 weight planes

// WB ushort offsets (hi/lo pairs; transposed (N,K) row-major; We2 padded to 192)
#define WB_W1H   0
#define WB_W1L   49152
#define WB_W2H   98304
#define WB_W2L   163840
#define WB_WE1H  229376
#define WB_WE1L  294912
#define WB_WE2H  360448
#define WB_WE2L  409600
#define WB_WQH   458752
#define WB_WQL   557056
#define WB_WKH   655360
#define WB_WKL   786432

typedef __attribute__((ext_vector_type(8))) short bf16x8;
typedef __attribute__((ext_vector_type(4))) float f32x4;

__device__ __forceinline__ ushort f2bf(float f){
  unsigned u = __float_as_uint(f);
  unsigned r = u + 0x7fffu + ((u>>16)&1u);
  return (ushort)(r>>16);
}
__device__ __forceinline__ float bf2f(ushort h){
  return __uint_as_float(((unsigned)h)<<16);
}
__device__ __forceinline__ void split2(float v, ushort &h, ushort &l){
  h = f2bf(v);
  l = f2bf(v - bf2f(h));
}

// ---------------- weight transpose+convert: Wt[n][k] = bf16(W[k][n]) --------
// rows n >= N are zero-padded (up to Npad)
__global__ __launch_bounds__(256) void wconv_kernel(
    const float* __restrict__ W, ushort* __restrict__ Whi,
    ushort* __restrict__ Wlo, int K, int N, int Npad)
{
  int idx = blockIdx.x*256 + threadIdx.x;
  if (idx >= Npad*K) return;
  int n = idx / K, k = idx - n*K;
  float v = (n < N) ? W[(size_t)k*N + n] : 0.f;
  ushort h = f2bf(v);
  Whi[idx] = h;
  Wlo[idx] = f2bf(v - bf2f(h));
}

// QK permuted variant: output col n' = (mh*4+dh)*16 + ml*4 + dl for
// n = m*16+d, m=mh*4+ml, d=dh*4+dl. Makes the d-reduction quad-local.
__global__ __launch_bounds__(256) void wconv_perm_kernel(
    const float* __restrict__ W, ushort* __restrict__ Whi,
    ushort* __restrict__ Wlo, int K)
{
  int idx = blockIdx.x*256 + threadIdx.x;
  if (idx >= 512*K) return;
  int n = idx / K, k = idx - n*K;
  float v = W[(size_t)k*512 + n];
  int m = n >> 4, d = n & 15;
  int npr = (((m>>2)*4 + (d>>2))<<4) | ((m&3)<<2) | (d&3);
  ushort h = f2bf(v);
  Whi[(size_t)npr*K + k] = h;
  Wlo[(size_t)npr*K + k] = f2bf(v - bf2f(h));
}

// ---------------- wide split-bf16 MFMA GEMM: full-N per block, 512 thr ------
// BM=128, BN=64*WNT (4 col-stripe waves x WNT 16-col tiles), BK=32,
// 8 waves in 2x4 grid (wm: rows 0-63/64-127, wn: col stripe).
// AMODE: 0 = A f32 row-major (split on the fly), 3 = A bf16 hi/lo pair
// OMODE: 0 = f32 C, 2 = bf16 hi/lo pair C
// LNEPI: fused LayerNorm(+bias)+cutoff epilogue (G2, needs BN=256), f32 C
template<int ACT, int AMODE, int OMODE, int WNT, int LNEPI>
__global__ __launch_bounds__(512,4) void gemm_wide(
    const void* __restrict__ Aptr, const void* __restrict__ Aptr2, int lda,
    const ushort* __restrict__ Bhi, const ushort* __restrict__ Blo, int Kdim,
    const float* __restrict__ bias,
    void* __restrict__ Cptr, void* __restrict__ Cptr2, int ldc, int Ncols,
    const float* __restrict__ lng, const float* __restrict__ lnb,
    const float* __restrict__ cut)
{
  constexpr int BN = 64*WNT;
  __shared__ ushort As[2][128][GA];
  __shared__ ushort Bs[2][BN][GA];
  __shared__ float sbuf[128][4];
  __shared__ float qbuf[128][4];
  const int tid  = threadIdx.x;
  const int row0 = blockIdx.x * 128;
  const int srow = tid >> 2;          // 0..127
  const int skc  = (tid & 3) * 8;     // 0,8,16,24
  const int wid  = tid >> 6, lane = tid & 63;
  const int wm   = wid >> 2, wn = wid & 3;
  const int lr   = lane & 15, kg = lane >> 4;

  f32x4 acc[4][WNT];
  #pragma unroll
  for (int mi=0;mi<4;++mi)
    #pragma unroll
    for (int ni=0;ni<WNT;++ni) acc[mi][ni] = (f32x4){0.f,0.f,0.f,0.f};

  for (int k0 = 0; k0 < Kdim; k0 += 32) {
    for (int br = srow; br < BN; br += 128) {
      *(bf16x8*)&Bs[0][br][skc] = *(const bf16x8*)(Bhi + (size_t)br*Kdim + k0 + skc);
      *(bf16x8*)&Bs[1][br][skc] = *(const bf16x8*)(Blo + (size_t)br*Kdim + k0 + skc);
    }
    {
      const int row = srow;
      if (AMODE == 3) {
        const size_t off = (size_t)(row0+row)*lda + k0 + skc;
        *(bf16x8*)&As[0][row][skc] = *(const bf16x8*)((const ushort*)Aptr + off);
        *(bf16x8*)&As[1][row][skc] = *(const bf16x8*)((const ushort*)Aptr2 + off);
      } else {
        const float* ap = (const float*)Aptr + (size_t)(row0+row)*lda + k0 + skc;
        float4 f0 = *(const float4*)ap;
        float4 f1 = *(const float4*)(ap+4);
        float vs[8] = {f0.x,f0.y,f0.z,f0.w,f1.x,f1.y,f1.z,f1.w};
        union { ushort u[8]; bf16x8 v; } th, tl;
        #pragma unroll
        for (int j=0;j<8;++j) split2(vs[j], th.u[j], tl.u[j]);
        *(bf16x8*)&As[0][row][skc] = th.v;
        *(bf16x8*)&As[1][row][skc] = tl.v;
      }
    }
    __syncthreads();
    bf16x8 ah[4], al[4];
    #pragma unroll
    for (int mi=0;mi<4;++mi) {
      ah[mi] = *(const bf16x8*)&As[0][wm*64 + mi*16 + lr][kg*8];
      al[mi] = *(const bf16x8*)&As[1][wm*64 + mi*16 + lr][kg*8];
    }
    #pragma unroll
    for (int ni=0;ni<WNT;++ni) {
      const int bro = wn*(16*WNT) + ni*16 + lr;
      bf16x8 bh = *(const bf16x8*)&Bs[0][bro][kg*8];
      bf16x8 bl = *(const bf16x8*)&Bs[1][bro][kg*8];
      #pragma unroll
      for (int mi=0;mi<4;++mi) {
        acc[mi][ni] = __builtin_amdgcn_mfma_f32_16x16x32_bf16(al[mi], bh, acc[mi][ni], 0, 0, 0);
        acc[mi][ni] = __builtin_amdgcn_mfma_f32_16x16x32_bf16(ah[mi], bl, acc[mi][ni], 0, 0, 0);
        acc[mi][ni] = __builtin_amdgcn_mfma_f32_16x16x32_bf16(ah[mi], bh, acc[mi][ni], 0, 0, 0);
      }
    }
    __syncthreads();
  }

  if (!LNEPI) {
    #pragma unroll
    for (int ni=0;ni<WNT;++ni) {
      const int col = wn*(16*WNT) + ni*16 + lr;
      const float bv = (col < Ncols) ? bias[col] : 0.f;
      #pragma unroll
      for (int mi=0;mi<4;++mi) {
        #pragma unroll
        for (int r=0;r<4;++r) {
          const int row = row0 + wm*64 + mi*16 + kg*4 + r;
          float v = acc[mi][ni][r] + bv;
          if (ACT == 1) v = v / (1.f + __expf(-v));
          const size_t oidx = (size_t)row*ldc + col;
          if (col < Ncols) {
            if (OMODE == 0) ((float*)Cptr)[oidx] = v;
            else {
              ushort h, l; split2(v, h, l);
              ((ushort*)Cptr)[oidx]  = h;
              ((ushort*)Cptr2)[oidx] = l;
            }
          }
        }
      }
    }
  } else {
    // fused bias + LayerNorm + cutoff epilogue (BN=256 covers full row)
    float bsv[WNT], gvv[WNT], bvv[WNT];
    #pragma unroll
    for (int ni=0;ni<WNT;++ni) {
      const int col = wn*(16*WNT) + ni*16 + lr;
      bsv[ni] = bias[col]; gvv[ni] = lng[col]; bvv[ni] = lnb[col];
    }
    #pragma unroll
    for (int mi=0;mi<4;++mi) {
      #pragma unroll
      for (int r=0;r<4;++r) {
        float s = 0.f, q = 0.f;
        #pragma unroll
        for (int ni=0;ni<WNT;++ni) {
          float v = acc[mi][ni][r] + bsv[ni];
          acc[mi][ni][r] = v;
          s += v; q += v*v;
        }
        s += __shfl_xor(s, 1); q += __shfl_xor(q, 1);
        s += __shfl_xor(s, 2); q += __shfl_xor(q, 2);
        s += __shfl_xor(s, 4); q += __shfl_xor(q, 4);
        s += __shfl_xor(s, 8); q += __shfl_xor(q, 8);
        if (lr == 0) {
          const int rl = wm*64 + mi*16 + kg*4 + r;
          sbuf[rl][wn] = s; qbuf[rl][wn] = q;
        }
      }
    }
    __syncthreads();
    #pragma unroll
    for (int mi=0;mi<4;++mi) {
      #pragma unroll
      for (int r=0;r<4;++r) {
        const int rl = wm*64 + mi*16 + kg*4 + r;
        const float S = sbuf[rl][0] + sbuf[rl][1] + sbuf[rl][2] + sbuf[rl][3];
        const float Q = qbuf[rl][0] + qbuf[rl][1] + qbuf[rl][2] + qbuf[rl][3];
        const float mean = S * (1.f/256.f);
        const float var  = Q * (1.f/256.f) - mean*mean;
        const float rs   = rsqrtf(var + 1e-5f);
        const float cutv = cut[row0 + rl];
        #pragma unroll
        for (int ni=0;ni<WNT;++ni) {
          const int col = wn*(16*WNT) + ni*16 + lr;
          float nv = (acc[mi][ni][r] - mean)*rs*gvv[ni] + bvv[ni];
          if (col < 128) nv *= cutv;
          ((float*)Cptr)[(size_t)(row0 + rl)*ldc + col] = nv;
        }
      }
    }
  }
}

// ---------------- fused QK attention logits (64 edges, 8 waves) -------------
// Block = 64 edges, 512 threads, wave grid 2(wm: 32-row halves) x 4(wn).
// Wave owns permuted tiles 8wn..8wn+7 over its 32 rows; wm-pair waves read
// IDENTICAL B addresses (L1 hits). A staged once in LDS (padded stride 264).
// B direct L2->VGPR, no barriers in MFMA loops. d-reduction: in-lane over
// dh + quad shfl_xor(1,2). 2 blocks/CU -> 4 waves/SIMD.
__global__ __launch_bounds__(512,4) void qk_att_kernel(
    const float* __restrict__ out, const float* __restrict__ ninv,
    const float* __restrict__ einv,
    const int* __restrict__ ctr, const int* __restrict__ nbr,
    const ushort* __restrict__ Wqh, const ushort* __restrict__ Wql,
    const ushort* __restrict__ Wkh, const ushort* __restrict__ Wkl,
    float* __restrict__ att)
{
  constexpr int ST = 264;            // padded row stride (ushorts)
  constexpr int PL = 64*ST;          // lo-plane offset
  __shared__ ushort Abuf[2*64*ST];   // 67.6 KB
  const int tid  = threadIdx.x;
  const int row0 = blockIdx.x * 64;
  const int wid  = tid >> 6;
  const int wm   = wid >> 2, wn = wid & 3;
  const int lane = tid & 63;
  const int lr   = lane & 15, kg = lane >> 4;

  // ---- stage efa (64 x 192 = 24 chunks of 8) hi/lo once ----
  {
    const int row = tid >> 3;         // 0..63
    const int ge  = row0 + row;
    const int ci  = ctr[ge], nn = nbr[ge];
    #pragma unroll
    for (int i = 0; i < 3; ++i) {
      const int q = (tid & 7) + 8*i;  // chunk 0..23 (k = q*8)
      const float* src;
      if (q < 8)       src = ninv + (size_t)ci*64 + q*8;
      else if (q < 16) src = ninv + (size_t)nn*64 + (q-8)*8;
      else             src = einv + (size_t)ge*64 + (q-16)*8;
      float4 f0 = *(const float4*)src;
      float4 f1 = *(const float4*)(src+4);
      float vs[8] = {f0.x,f0.y,f0.z,f0.w,f1.x,f1.y,f1.z,f1.w};
      union { ushort u[8]; bf16x8 v; } th, tl;
      #pragma unroll
      for (int j=0;j<8;++j) split2(vs[j], th.u[j], tl.u[j]);
      *(bf16x8*)&Abuf[row*ST + q*8]      = th.v;
      *(bf16x8*)&Abuf[PL + row*ST + q*8] = tl.v;
    }
  }
  __syncthreads();

  // ---- phase Q: accQ[8 tiles][2 mi], k0-outer, zero barriers ----
  f32x4 accQ[8][2];
  #pragma unroll
  for (int t=0;t<8;++t)
    #pragma unroll
    for (int mi=0;mi<2;++mi) accQ[t][mi] = (f32x4){0.f,0.f,0.f,0.f};

  #pragma unroll
  for (int k0 = 0; k0 < 6; ++k0) {
    bf16x8 ah[2], al[2];
    #pragma unroll
    for (int mi=0;mi<2;++mi) {
      const int row = wm*32 + mi*16 + lr;
      ah[mi] = *(const bf16x8*)&Abuf[row*ST + k0*32 + kg*8];
      al[mi] = *(const bf16x8*)&Abuf[PL + row*ST + k0*32 + kg*8];
    }
    #pragma unroll
    for (int tl = 0; tl < 8; ++tl) {
      const size_t boff = (size_t)((wn*8 + tl)*16 + lr)*192 + k0*32 + kg*8;
      bf16x8 bh = *(const bf16x8*)(Wqh + boff);
      bf16x8 bl = *(const bf16x8*)(Wql + boff);
      #pragma unroll
      for (int mi=0;mi<2;++mi) {
        accQ[tl][mi] = __builtin_amdgcn_mfma_f32_16x16x32_bf16(al[mi], bh, accQ[tl][mi], 0, 0, 0);
        accQ[tl][mi] = __builtin_amdgcn_mfma_f32_16x16x32_bf16(ah[mi], bl, accQ[tl][mi], 0, 0, 0);
        accQ[tl][mi] = __builtin_amdgcn_mfma_f32_16x16x32_bf16(ah[mi], bh, accQ[tl][mi], 0, 0, 0);
      }
    }
  }

  // ---- restage A with latents (64 x 256 = 32 chunks) ----
  __syncthreads();
  {
    const int row = tid >> 3;
    const float* src0 = out + (size_t)(row0 + row)*OUT_D;
    #pragma unroll
    for (int i = 0; i < 4; ++i) {
      const int q = (tid & 7) + 8*i;  // chunk 0..31
      float4 f0 = *(const float4*)(src0 + q*8);
      float4 f1 = *(const float4*)(src0 + q*8 + 4);
      float vs[8] = {f0.x,f0.y,f0.z,f0.w,f1.x,f1.y,f1.z,f1.w};
      union { ushort u[8]; bf16x8 v; } th, tl;
      #pragma unroll
      for (int j=0;j<8;++j) split2(vs[j], th.u[j], tl.u[j]);
      *(bf16x8*)&Abuf[row*ST + q*8]      = th.v;
      *(bf16x8*)&Abuf[PL + row*ST + q*8] = tl.v;
    }
  }
  __syncthreads();

  // ---- phase K in 2 passes of 4 dh-tiles; combine in-lane + quad DPP ----
  #pragma unroll
  for (int p = 0; p < 2; ++p) {
    f32x4 accK[4][2];
    #pragma unroll
    for (int dh=0;dh<4;++dh)
      #pragma unroll
      for (int mi=0;mi<2;++mi) accK[dh][mi] = (f32x4){0.f,0.f,0.f,0.f};
    #pragma unroll
    for (int k0 = 0; k0 < 8; ++k0) {
      bf16x8 ah[2], al[2];
      #pragma unroll
      for (int mi=0;mi<2;++mi) {
        const int row = wm*32 + mi*16 + lr;
        ah[mi] = *(const bf16x8*)&Abuf[row*ST + k0*32 + kg*8];
        al[mi] = *(const bf16x8*)&Abuf[PL + row*ST + k0*32 + kg*8];
      }
      #pragma unroll
      for (int dh = 0; dh < 4; ++dh) {
        const size_t boff = (size_t)((wn*8 + p*4 + dh)*16 + lr)*256 + k0*32 + kg*8;
        bf16x8 bh = *(const bf16x8*)(Wkh + boff);
        bf16x8 bl = *(const bf16x8*)(Wkl + boff);
        #pragma unroll
        for (int mi=0;mi<2;++mi) {
          accK[dh][mi] = __builtin_amdgcn_mfma_f32_16x16x32_bf16(al[mi], bh, accK[dh][mi], 0, 0, 0);
          accK[dh][mi] = __builtin_amdgcn_mfma_f32_16x16x32_bf16(ah[mi], bl, accK[dh][mi], 0, 0, 0);
          accK[dh][mi] = __builtin_amdgcn_mfma_f32_16x16x32_bf16(ah[mi], bh, accK[dh][mi], 0, 0, 0);
        }
      }
    }
    // combine: att[e, m] = 4 * sum_d Q*K; m = (2wn+p)*4 + (lr>>2)
    const int m = (2*wn + p)*4 + (lr >> 2);
    #pragma unroll
    for (int mi=0;mi<2;++mi) {
      float s[4];
      #pragma unroll
      for (int r=0;r<4;++r) {
        s[r] = accQ[p*4+0][mi][r]*accK[0][mi][r]
             + accQ[p*4+1][mi][r]*accK[1][mi][r]
             + accQ[p*4+2][mi][r]*accK[2][mi][r]
             + accQ[p*4+3][mi][r]*accK[3][mi][r];
      }
      #pragma unroll
      for (int r=0;r<4;++r) {
        s[r] += __shfl_xor(s[r], 1);
        s[r] += __shfl_xor(s[r], 2);
      }
      if ((lr & 3) == 0) {
        #pragma unroll
        for (int r=0;r<4;++r) {
          const int row = row0 + wm*32 + mi*16 + kg*4 + r;
          att[(size_t)row*32 + m] = 4.0f * s[r];
        }
      }
    }
  }
}

// ---------------- CSR build: histogram / scan / scatter ---------------------
__global__ __launch_bounds__(256) void hist_kernel(
    const int* __restrict__ ctr, int* __restrict__ cnt)
{
  int e = blockIdx.x*256 + threadIdx.x;
  if (e < E_EDGES) atomicAdd(&cnt[ctr[e]], 1);
}

__global__ __launch_bounds__(256) void scan_kernel(
    const int* __restrict__ cnt, int* __restrict__ rowptr,
    int* __restrict__ cursor)
{
  __shared__ int part[256];
  const int t = threadIdx.x;
  const int base = t*32;
  int local[32];
  int s = 0;
  #pragma unroll
  for (int k=0;k<32;++k){ local[k]=cnt[base+k]; s+=local[k]; }
  part[t]=s; __syncthreads();
  for (int off=1; off<256; off<<=1){
    int v = (t>=off)? part[t-off] : 0;
    __syncthreads();
    part[t]+=v;
    __syncthreads();
  }
  int run = (t==0)?0:part[t-1];
  #pragma unroll
  for (int k=0;k<32;++k){ rowptr[base+k]=run; cursor[base+k]=run; run+=local[k]; }
  if (t==255) rowptr[N_NODES]=run;
}

__global__ __launch_bounds__(256) void scatter_kernel(
    const int* __restrict__ ctr, int* __restrict__ cursor,
    int* __restrict__ eidx)
{
  int e = blockIdx.x*256 + threadIdx.x;
  if (e < E_EDGES){ int p = atomicAdd(&cursor[ctr[e]],1); eidx[p]=e; }
}

// ---------------- fused per-node: softmax + env accum + so3_norm + mixing ---
__global__ __launch_bounds__(128) void node_env_kernel(
    const float* __restrict__ att, const int* __restrict__ eidx,
    const int* __restrict__ rowptr, const float* __restrict__ eattr,
    const float* __restrict__ outbuf,
    const float* __restrict__ env_nw, const float* __restrict__ env_lw,
    float* __restrict__ env2)
{
  __shared__ float mx_s[32], rs_s[32];
  __shared__ float jm[4][32], js[4][32];
  __shared__ float ev[128];
  __shared__ float2 red[128];
  const int n = blockIdx.x, t = threadIdx.x;
  const int start = rowptr[n], deg = rowptr[n+1] - start;
  {
    const int m = t & 31, j = t >> 5;
    float lm = -3.4e38f, ls = 0.f;
    for (int i = j; i < deg; i += 4) {
      float l = att[(size_t)eidx[start+i]*32 + m];
      if (l > lm) { ls = ls * __expf(lm - l) + 1.f; lm = l; }
      else ls += __expf(l - lm);
    }
    jm[j][m] = lm; js[j][m] = ls;
  }
  __syncthreads();
  if (t < 32) {
    const int m = t;
    float M = jm[0][m];
    #pragma unroll
    for (int q=1;q<4;++q) M = fmaxf(M, jm[q][m]);
    float S = 0.f;
    #pragma unroll
    for (int q=0;q<4;++q) S += js[q][m] * __expf(jm[q][m] - M);
    mx_s[m] = M;
    rs_s[m] = 1.f / (S + 1e-16f);
  }
  __syncthreads();
  const int m2 = t >> 2, d = t & 3;
  const float M2 = mx_s[m2], R2 = rs_s[m2];
  float acc = 0.f;
  for (int i = 0; i < deg; ++i) {
    const int e = eidx[start+i];
    float a = __expf(att[(size_t)e*32 + m2] - M2) * R2;
    const float* wr = outbuf + (size_t)e*OUT_D + 256;
    float w = (d==0) ? wr[64 + 2*m2] : wr[65 + 2*m2];
    float sc = wr[128 + m2];
    float ea = eattr[(size_t)e*128 + m2*4 + d];
    acc += ea * w * sc * a;
  }
  float val = acc;
  red[t] = make_float2(d==0 ? val*val : 0.f, d!=0 ? val*val : 0.f);
  __syncthreads();
  for (int off=64; off>0; off>>=1) {
    if (t<off){ red[t].x += red[t+off].x; red[t].y += red[t+off].y; }
    __syncthreads();
  }
  float inv_s = rsqrtf(red[0].x*(1.f/32.f)+EPS6);
  float inv_v = rsqrtf(red[0].y*(1.f/96.f)+EPS6);
  float nv = (d==0) ? val*inv_s*env_nw[2*m2] : val*inv_v*env_nw[2*m2+1];
  ev[t] = nv;
  __syncthreads();
  const float* WL = env_lw + (d==0 ? 0 : 1024);
  float a2 = 0.f;
  #pragma unroll 8
  for (int q=0;q<32;++q) a2 += ev[q*4+d]*WL[q*32+m2];
  env2[(size_t)n*128 + m2*4 + d] = a2;
}

// ---------------- per-edge tensor product: 32 lanes/edge, 8 edges/block -----
__global__ __launch_bounds__(256) void edge_final_kernel(
    const float* __restrict__ eq_feat, const float* __restrict__ env2,
    const int* __restrict__ ctr,
    const float* __restrict__ eq_norm_w, const float* __restrict__ tp_norm_w,
    const float* __restrict__ lin_vec_w, float* __restrict__ out)
{
  __shared__ float Wv[96*32];
  __shared__ float ov[8][96][3];
  const int tid = threadIdx.x;
  for (int i = tid; i < 96*32; i += 256) Wv[i] = lin_vec_w[i];
  __syncthreads();
  const int grp = tid >> 5;
  const int m   = tid & 31;
  const int e   = blockIdx.x*8 + grp;
  float* wrow = out + (size_t)e*OUT_D;

  float4 x   = *(const float4*)(eq_feat + ((size_t)e*32 + m)*4);
  float2 w01 = *(const float2*)(wrow + 256 + 2*m);
  float sw = x.x*w01.x, v0 = x.y*w01.y, v1 = x.z*w01.y, v2 = x.w*w01.y;
  const int nidx = ctr[e];
  float4 evv = *(const float4*)(env2 + (size_t)nidx*128 + m*4);

  float ps_ = sw*sw, pv_ = v0*v0 + v1*v1 + v2*v2;
  #pragma unroll
  for (int off=16; off; off>>=1) {
    ps_ += __shfl_xor(ps_, off, 32);
    pv_ += __shfl_xor(pv_, off, 32);
  }
  float inv_s = rsqrtf(ps_*(1.f/32.f)+EPS6);
  float inv_v = rsqrtf(pv_*(1.f/96.f)+EPS6);
  float s  = sw*inv_s*eq_norm_w[2*m];
  float fv = inv_v*eq_norm_w[2*m+1];
  v0 *= fv; v1 *= fv; v2 *= fv;
  float es = evv.x, e0 = evv.y, e1 = evv.z, e2 = evv.w;
  float os0 = s*es;
  float os1 = (v0*e0 + v1*e1 + v2*e2) * 0.5773502691896258f;
  float a00=s*e0, a01=s*e1, a02=s*e2;
  float a10=v0*es, a11=v1*es, a12=v2*es;
  const float is2 = 0.7071067811865476f;
  float a20=(v1*e2 - v2*e1)*is2;
  float a21=(v2*e0 - v0*e2)*is2;
  float a22=(v0*e1 - v1*e0)*is2;
  float q0 = os0*os0, q1 = os1*os1;
  float q2 = a00*a00+a01*a01+a02*a02;
  float q3 = a10*a10+a11*a11+a12*a12;
  float q4 = a20*a20+a21*a21+a22*a22;
  #pragma unroll
  for (int off=16; off; off>>=1) {
    q0 += __shfl_xor(q0, off, 32); q1 += __shfl_xor(q1, off, 32);
    q2 += __shfl_xor(q2, off, 32); q3 += __shfl_xor(q3, off, 32);
    q4 += __shfl_xor(q4, off, 32);
  }
  float t0 = rsqrtf(q0*(1.f/32.f)+EPS6)*tp_norm_w[m*5+0];
  float t1 = rsqrtf(q1*(1.f/32.f)+EPS6)*tp_norm_w[m*5+1];
  float f0 = rsqrtf(q2*(1.f/96.f)+EPS6)*tp_norm_w[m*5+2];
  float f1 = rsqrtf(q3*(1.f/96.f)+EPS6)*tp_norm_w[m*5+3];
  float f2 = rsqrtf(q4*(1.f/96.f)+EPS6)*tp_norm_w[m*5+4];

  *(float2*)(wrow + 256 + 2*m) = make_float2(os0*t0, os1*t1);
  ov[grp][3*m+0][0]=a00*f0; ov[grp][3*m+0][1]=a01*f0; ov[grp][3*m+0][2]=a02*f0;
  ov[grp][3*m+1][0]=a10*f1; ov[grp][3*m+1][1]=a11*f1; ov[grp][3*m+1][2]=a12*f1;
  ov[grp][3*m+2][0]=a20*f2; ov[grp][3*m+2][1]=a21*f2; ov[grp][3*m+2][2]=a22*f2;
  float acc0=0.f, acc1=0.f, acc2=0.f;
  #pragma unroll 4
  for (int i=0;i<96;++i) {
    float wv = Wv[i*32 + m];
    acc0 += ov[grp][i][0]*wv;
    acc1 += ov[grp][i][1]*wv;
    acc2 += ov[grp][i][2]*wv;
  }
  wrow[320 + 3*m + 0] = acc0;
  wrow[320 + 3*m + 1] = acc1;
  wrow[320 + 3*m + 2] = acc2;
}

// =============================================================================
extern "C" void kernel_launch(void* const* d_in, const int* in_sizes, int n_in,
                              void* d_out, int out_size, void* d_ws, size_t ws_size,
                              hipStream_t stream)
{
  (void)in_sizes; (void)n_in; (void)out_size; (void)ws_size;
  const float* x      = (const float*)d_in[0];
  const float* cut    = (const float*)d_in[1];
  const float* eqf    = (const float*)d_in[2];
  const float* eattr  = (const float*)d_in[3];
  const float* ninv   = (const float*)d_in[4];
  const float* einv   = (const float*)d_in[5];
  const float* W1     = (const float*)d_in[6];
  const float* b1     = (const float*)d_in[7];
  const float* W2     = (const float*)d_in[8];
  const float* b2     = (const float*)d_in[9];
  const float* ln_g   = (const float*)d_in[10];
  const float* ln_b   = (const float*)d_in[11];
  const float* We1    = (const float*)d_in[12];
  const float* be1    = (const float*)d_in[13];
  const float* We2    = (const float*)d_in[14];
  const float* be2    = (const float*)d_in[15];
  const float* Wq     = (const float*)d_in[16];
  const float* Wk     = (const float*)d_in[17];
  const float* eq_nw  = (const float*)d_in[18];
  const float* env_nw = (const float*)d_in[19];
  const float* env_lw = (const float*)d_in[20];
  const float* tp_nw  = (const float*)d_in[21];
  const float* lin_vw = (const float*)d_in[22];
  const int*   ctr    = (const int*)d_in[23];
  const int*   nbr    = (const int*)d_in[24];

  float* out = (float*)d_out;
  float* ws  = (float*)d_ws;
  ushort* Hhi   = (ushort*)(ws + WS_HHI);
  ushort* Hlo   = (ushort*)(ws + WS_HLO);
  float* att    = ws + WS_ATT;
  float* env2   = ws + WS_ENV2;
  int* cnt      = (int*)(ws + WS_CNT);
  int* rowptr   = (int*)(ws + WS_ROWPTR);
  int* cursor   = (int*)(ws + WS_CURSOR);
  int* eidx     = (int*)(ws + WS_EIDX);
  ushort* WB    = (ushort*)(ws + WS_WB);

  hipMemsetAsync(cnt, 0, N_NODES*sizeof(int), stream);

  // CSR build
  hist_kernel<<<E_EDGES/256, 256, 0, stream>>>(ctr, cnt);
  scan_kernel<<<1, 256, 0, stream>>>(cnt, rowptr, cursor);
  scatter_kernel<<<E_EDGES/256, 256, 0, stream>>>(ctr, cursor, eidx);

  // weight conversion (transposed, hi/lo planes; We2 zero-padded to 192 rows;
  // Wq/Wk with QK permutation)
  wconv_kernel<<<192, 256, 0, stream>>>(W1,  WB+WB_W1H,  WB+WB_W1L,  192, 256, 256);
  wconv_kernel<<<256, 256, 0, stream>>>(W2,  WB+WB_W2H,  WB+WB_W2L,  256, 256, 256);
  wconv_kernel<<<256, 256, 0, stream>>>(We1, WB+WB_WE1H, WB+WB_WE1L, 256, 256, 256);
  wconv_kernel<<<192, 256, 0, stream>>>(We2, WB+WB_WE2H, WB+WB_WE2L, 256, 160, 192);
  wconv_perm_kernel<<<384, 256, 0, stream>>>(Wq, WB+WB_WQH, WB+WB_WQL, 192);
  wconv_perm_kernel<<<512, 256, 0, stream>>>(Wk, WB+WB_WKH, WB+WB_WKL, 256);

  // G1: silu(x @ W1 + b1) -> H hi/lo
  gemm_wide<1,0,2,4,0><<<E_EDGES/128, 512, 0, stream>>>(
      x, nullptr, D_INF, WB+WB_W1H, WB+WB_W1L, 192, b1,
      Hhi, Hlo, 256, 256, nullptr, nullptr, nullptr);
  // G2: H @ W2 + b2, fused LayerNorm+cutoff -> out cols 0..255 (f32)
  gemm_wide<0,3,0,4,1><<<E_EDGES/128, 512, 0, stream>>>(
      Hhi, Hlo, 256, WB+WB_W2H, WB+WB_W2L, 256, b2,
      out, nullptr, OUT_D, 256, ln_g, ln_b, cut);
  // fused QK -> att (64-edge blocks, 512 threads, 4 waves/SIMD)
  qk_att_kernel<<<E_EDGES/64, 512, 0, stream>>>(
      out, ninv, einv, ctr, nbr,
      WB+WB_WQH, WB+WB_WQL, WB+WB_WKH, WB+WB_WKL, att);
  // G3: silu(lat @ We1 + be1) -> H hi/lo (reuse)
  gemm_wide<1,0,2,4,0><<<E_EDGES/128, 512, 0, stream>>>(
      out, nullptr, OUT_D, WB+WB_WE1H, WB+WB_WE1L, 256, be1,
      Hhi, Hlo, 256, 256, nullptr, nullptr, nullptr);
  // G4: H @ We2 + be2 -> out cols 256..415 (f32, N=160, B padded to 192)
  gemm_wide<0,3,0,3,0><<<E_EDGES/128, 512, 0, stream>>>(
      Hhi, Hlo, 256, WB+WB_WE2H, WB+WB_WE2L, 256, be2,
      out + 256, nullptr, OUT_D, 160, nullptr, nullptr, nullptr);
  // fused per-node softmax + env + norm + mixing
  node_env_kernel<<<N_NODES, 128, 0, stream>>>(att, eidx, rowptr, eattr, out,
                                               env_nw, env_lw, env2);
  // final per-edge tensor product
  edge_final_kernel<<<E_EDGES/8, 256, 0, stream>>>(eqf, env2, ctr, eq_nw, tp_nw, lin_vw, out);
}

// Round 12
// 836.598 us; speedup vs baseline: 1.2209x; 1.2209x over previous
//
#include <hip/hip_runtime.h>
#include <cstddef>
#include <cstdint>

// Problem constants (fixed by setup_inputs)
#define E_EDGES 131072
#define N_NODES 8192
#define D_INF   192
#define L_DIM   256
#define OUT_D   416
#define EPS6    1e-6f
#define GA      40            // LDS row stride (shorts) for gemm_wide tiles

// ws layout (float offsets)
#define WS_HHI   0ull          // E*256 bf16 hi plane (G1/G3 out)
#define WS_HLO   16777216ull   // E*256 bf16 lo plane
#define WS_ATT   33554432ull   // E*32 f32 logits
#define WS_ENV2  37748736ull   // N*128 f32
#define WS_CNT   38797312ull   // N int
#define WS_ROWPTR 38805504ull  // N+1 int (padded)
#define WS_CURSOR 38813760ull  // N int
#define WS_EIDX  38821952ull   // E int
#define WS_WB    38953024ull   // bf16 weight planes

// WB ushort offsets (hi/lo pairs; transposed (N,K) row-major; We2 padded to 192)
#define WB_W1H   0
#define WB_W1L   49152
#define WB_W2H   98304
#define WB_W2L   163840
#define WB_WE1H  229376
#define WB_WE1L  294912
#define WB_WE2H  360448
#define WB_WE2L  409600
#define WB_WQH   458752
#define WB_WQL   557056
#define WB_WKH   655360
#define WB_WKL   786432

typedef __attribute__((ext_vector_type(8))) short bf16x8;
typedef __attribute__((ext_vector_type(4))) float f32x4;

__device__ __forceinline__ ushort f2bf(float f){
  unsigned u = __float_as_uint(f);
  unsigned r = u + 0x7fffu + ((u>>16)&1u);
  return (ushort)(r>>16);
}
__device__ __forceinline__ float bf2f(ushort h){
  return __uint_as_float(((unsigned)h)<<16);
}
__device__ __forceinline__ void split2(float v, ushort &h, ushort &l){
  h = f2bf(v);
  l = f2bf(v - bf2f(h));
}

// ---------------- weight transpose+convert: Wt[n][k] = bf16(W[k][n]) --------
// rows n >= N are zero-padded (up to Npad)
__global__ __launch_bounds__(256) void wconv_kernel(
    const float* __restrict__ W, ushort* __restrict__ Whi,
    ushort* __restrict__ Wlo, int K, int N, int Npad)
{
  int idx = blockIdx.x*256 + threadIdx.x;
  if (idx >= Npad*K) return;
  int n = idx / K, k = idx - n*K;
  float v = (n < N) ? W[(size_t)k*N + n] : 0.f;
  ushort h = f2bf(v);
  Whi[idx] = h;
  Wlo[idx] = f2bf(v - bf2f(h));
}

// QK permuted variant: output col n' = (mh*4+dh)*16 + ml*4 + dl for
// n = m*16+d, m=mh*4+ml, d=dh*4+dl. Makes the d-reduction quad-local.
__global__ __launch_bounds__(256) void wconv_perm_kernel(
    const float* __restrict__ W, ushort* __restrict__ Whi,
    ushort* __restrict__ Wlo, int K)
{
  int idx = blockIdx.x*256 + threadIdx.x;
  if (idx >= 512*K) return;
  int n = idx / K, k = idx - n*K;
  float v = W[(size_t)k*512 + n];
  int m = n >> 4, d = n & 15;
  int npr = (((m>>2)*4 + (d>>2))<<4) | ((m&3)<<2) | (d&3);
  ushort h = f2bf(v);
  Whi[(size_t)npr*K + k] = h;
  Wlo[(size_t)npr*K + k] = f2bf(v - bf2f(h));
}

// ---------------- wide split-bf16 MFMA GEMM: full-N per block, 512 thr ------
// BM=128, BN=64*WNT (4 col-stripe waves x WNT 16-col tiles), BK=32,
// 8 waves in 2x4 grid (wm: rows 0-63/64-127, wn: col stripe).
// AMODE: 0 = A f32 row-major (split on the fly), 3 = A bf16 hi/lo pair
// OMODE: 0 = f32 C, 2 = bf16 hi/lo pair C
// LNEPI: fused LayerNorm(+bias)+cutoff epilogue (G2, needs BN=256), f32 C
template<int ACT, int AMODE, int OMODE, int WNT, int LNEPI>
__global__ __launch_bounds__(512,4) void gemm_wide(
    const void* __restrict__ Aptr, const void* __restrict__ Aptr2, int lda,
    const ushort* __restrict__ Bhi, const ushort* __restrict__ Blo, int Kdim,
    const float* __restrict__ bias,
    void* __restrict__ Cptr, void* __restrict__ Cptr2, int ldc, int Ncols,
    const float* __restrict__ lng, const float* __restrict__ lnb,
    const float* __restrict__ cut)
{
  constexpr int BN = 64*WNT;
  __shared__ ushort As[2][128][GA];
  __shared__ ushort Bs[2][BN][GA];
  __shared__ float sbuf[128][4];
  __shared__ float qbuf[128][4];
  const int tid  = threadIdx.x;
  const int row0 = blockIdx.x * 128;
  const int srow = tid >> 2;          // 0..127
  const int skc  = (tid & 3) * 8;     // 0,8,16,24
  const int wid  = tid >> 6, lane = tid & 63;
  const int wm   = wid >> 2, wn = wid & 3;
  const int lr   = lane & 15, kg = lane >> 4;

  f32x4 acc[4][WNT];
  #pragma unroll
  for (int mi=0;mi<4;++mi)
    #pragma unroll
    for (int ni=0;ni<WNT;++ni) acc[mi][ni] = (f32x4){0.f,0.f,0.f,0.f};

  for (int k0 = 0; k0 < Kdim; k0 += 32) {
    for (int br = srow; br < BN; br += 128) {
      *(bf16x8*)&Bs[0][br][skc] = *(const bf16x8*)(Bhi + (size_t)br*Kdim + k0 + skc);
      *(bf16x8*)&Bs[1][br][skc] = *(const bf16x8*)(Blo + (size_t)br*Kdim + k0 + skc);
    }
    {
      const int row = srow;
      if (AMODE == 3) {
        const size_t off = (size_t)(row0+row)*lda + k0 + skc;
        *(bf16x8*)&As[0][row][skc] = *(const bf16x8*)((const ushort*)Aptr + off);
        *(bf16x8*)&As[1][row][skc] = *(const bf16x8*)((const ushort*)Aptr2 + off);
      } else {
        const float* ap = (const float*)Aptr + (size_t)(row0+row)*lda + k0 + skc;
        float4 f0 = *(const float4*)ap;
        float4 f1 = *(const float4*)(ap+4);
        float vs[8] = {f0.x,f0.y,f0.z,f0.w,f1.x,f1.y,f1.z,f1.w};
        union { ushort u[8]; bf16x8 v; } th, tl;
        #pragma unroll
        for (int j=0;j<8;++j) split2(vs[j], th.u[j], tl.u[j]);
        *(bf16x8*)&As[0][row][skc] = th.v;
        *(bf16x8*)&As[1][row][skc] = tl.v;
      }
    }
    __syncthreads();
    bf16x8 ah[4], al[4];
    #pragma unroll
    for (int mi=0;mi<4;++mi) {
      ah[mi] = *(const bf16x8*)&As[0][wm*64 + mi*16 + lr][kg*8];
      al[mi] = *(const bf16x8*)&As[1][wm*64 + mi*16 + lr][kg*8];
    }
    #pragma unroll
    for (int ni=0;ni<WNT;++ni) {
      const int bro = wn*(16*WNT) + ni*16 + lr;
      bf16x8 bh = *(const bf16x8*)&Bs[0][bro][kg*8];
      bf16x8 bl = *(const bf16x8*)&Bs[1][bro][kg*8];
      #pragma unroll
      for (int mi=0;mi<4;++mi) {
        acc[mi][ni] = __builtin_amdgcn_mfma_f32_16x16x32_bf16(al[mi], bh, acc[mi][ni], 0, 0, 0);
        acc[mi][ni] = __builtin_amdgcn_mfma_f32_16x16x32_bf16(ah[mi], bl, acc[mi][ni], 0, 0, 0);
        acc[mi][ni] = __builtin_amdgcn_mfma_f32_16x16x32_bf16(ah[mi], bh, acc[mi][ni], 0, 0, 0);
      }
    }
    __syncthreads();
  }

  if (!LNEPI) {
    #pragma unroll
    for (int ni=0;ni<WNT;++ni) {
      const int col = wn*(16*WNT) + ni*16 + lr;
      const float bv = (col < Ncols) ? bias[col] : 0.f;
      #pragma unroll
      for (int mi=0;mi<4;++mi) {
        #pragma unroll
        for (int r=0;r<4;++r) {
          const int row = row0 + wm*64 + mi*16 + kg*4 + r;
          float v = acc[mi][ni][r] + bv;
          if (ACT == 1) v = v / (1.f + __expf(-v));
          const size_t oidx = (size_t)row*ldc + col;
          if (col < Ncols) {
            if (OMODE == 0) ((float*)Cptr)[oidx] = v;
            else {
              ushort h, l; split2(v, h, l);
              ((ushort*)Cptr)[oidx]  = h;
              ((ushort*)Cptr2)[oidx] = l;
            }
          }
        }
      }
    }
  } else {
    // fused bias + LayerNorm + cutoff epilogue (BN=256 covers full row)
    float bsv[WNT], gvv[WNT], bvv[WNT];
    #pragma unroll
    for (int ni=0;ni<WNT;++ni) {
      const int col = wn*(16*WNT) + ni*16 + lr;
      bsv[ni] = bias[col]; gvv[ni] = lng[col]; bvv[ni] = lnb[col];
    }
    #pragma unroll
    for (int mi=0;mi<4;++mi) {
      #pragma unroll
      for (int r=0;r<4;++r) {
        float s = 0.f, q = 0.f;
        #pragma unroll
        for (int ni=0;ni<WNT;++ni) {
          float v = acc[mi][ni][r] + bsv[ni];
          acc[mi][ni][r] = v;
          s += v; q += v*v;
        }
        s += __shfl_xor(s, 1); q += __shfl_xor(q, 1);
        s += __shfl_xor(s, 2); q += __shfl_xor(q, 2);
        s += __shfl_xor(s, 4); q += __shfl_xor(q, 4);
        s += __shfl_xor(s, 8); q += __shfl_xor(q, 8);
        if (lr == 0) {
          const int rl = wm*64 + mi*16 + kg*4 + r;
          sbuf[rl][wn] = s; qbuf[rl][wn] = q;
        }
      }
    }
    __syncthreads();
    #pragma unroll
    for (int mi=0;mi<4;++mi) {
      #pragma unroll
      for (int r=0;r<4;++r) {
        const int rl = wm*64 + mi*16 + kg*4 + r;
        const float S = sbuf[rl][0] + sbuf[rl][1] + sbuf[rl][2] + sbuf[rl][3];
        const float Q = qbuf[rl][0] + qbuf[rl][1] + qbuf[rl][2] + qbuf[rl][3];
        const float mean = S * (1.f/256.f);
        const float var  = Q * (1.f/256.f) - mean*mean;
        const float rs   = rsqrtf(var + 1e-5f);
        const float cutv = cut[row0 + rl];
        #pragma unroll
        for (int ni=0;ni<WNT;++ni) {
          const int col = wn*(16*WNT) + ni*16 + lr;
          float nv = (acc[mi][ni][r] - mean)*rs*gvv[ni] + bvv[ni];
          if (col < 128) nv *= cutv;
          ((float*)Cptr)[(size_t)(row0 + rl)*ldc + col] = nv;
        }
      }
    }
  }
}

// ---------------- fused QK attention logits (R9 config: best measured) ------
// Block = 64 edges, 4 waves (wave = col stripe); wave owns permuted tiles
// 8wn..8wn+7 (4m x 4d cols each). A staged once in LDS (padded stride 264).
// B direct L2->VGPR, no barriers in MFMA loops. d-reduction: in-lane over
// dh + quad shfl_xor(1,2). VGPR 128, no spills.
__global__ __launch_bounds__(256,2) void qk_att_kernel(
    const float* __restrict__ out, const float* __restrict__ ninv,
    const float* __restrict__ einv,
    const int* __restrict__ ctr, const int* __restrict__ nbr,
    const ushort* __restrict__ Wqh, const ushort* __restrict__ Wql,
    const ushort* __restrict__ Wkh, const ushort* __restrict__ Wkl,
    float* __restrict__ att)
{
  constexpr int ST = 264;            // padded row stride (ushorts)
  constexpr int PL = 64*ST;          // lo-plane offset
  __shared__ ushort Abuf[2*64*ST];   // 67.6 KB
  const int tid  = threadIdx.x;
  const int row0 = blockIdx.x * 64;
  const int wn   = tid >> 6;
  const int lane = tid & 63;
  const int lr   = lane & 15, kg = lane >> 4;

  // ---- stage efa (64 x 192 = 24 chunks of 8) hi/lo once ----
  {
    const int row = tid >> 2;         // 0..63
    const int ge  = row0 + row;
    const int ci  = ctr[ge], nn = nbr[ge];
    #pragma unroll
    for (int i = 0; i < 6; ++i) {
      const int q = (tid & 3) + 4*i;  // chunk 0..23 (k = q*8)
      const float* src;
      if (q < 8)       src = ninv + (size_t)ci*64 + q*8;
      else if (q < 16) src = ninv + (size_t)nn*64 + (q-8)*8;
      else             src = einv + (size_t)ge*64 + (q-16)*8;
      float4 f0 = *(const float4*)src;
      float4 f1 = *(const float4*)(src+4);
      float vs[8] = {f0.x,f0.y,f0.z,f0.w,f1.x,f1.y,f1.z,f1.w};
      union { ushort u[8]; bf16x8 v; } th, tl;
      #pragma unroll
      for (int j=0;j<8;++j) split2(vs[j], th.u[j], tl.u[j]);
      *(bf16x8*)&Abuf[row*ST + q*8]      = th.v;
      *(bf16x8*)&Abuf[PL + row*ST + q*8] = tl.v;
    }
  }
  __syncthreads();

  // ---- phase Q: accQ[8 tiles][4 mi], k0-outer, zero barriers ----
  f32x4 accQ[8][4];
  #pragma unroll
  for (int t=0;t<8;++t)
    #pragma unroll
    for (int mi=0;mi<4;++mi) accQ[t][mi] = (f32x4){0.f,0.f,0.f,0.f};

  #pragma unroll
  for (int k0 = 0; k0 < 6; ++k0) {
    bf16x8 ah[4], al[4];
    #pragma unroll
    for (int mi=0;mi<4;++mi) {
      const int row = mi*16 + lr;
      ah[mi] = *(const bf16x8*)&Abuf[row*ST + k0*32 + kg*8];
      al[mi] = *(const bf16x8*)&Abuf[PL + row*ST + k0*32 + kg*8];
    }
    #pragma unroll
    for (int tl = 0; tl < 8; ++tl) {
      const size_t boff = (size_t)((wn*8 + tl)*16 + lr)*192 + k0*32 + kg*8;
      bf16x8 bh = *(const bf16x8*)(Wqh + boff);
      bf16x8 bl = *(const bf16x8*)(Wql + boff);
      #pragma unroll
      for (int mi=0;mi<4;++mi) {
        accQ[tl][mi] = __builtin_amdgcn_mfma_f32_16x16x32_bf16(al[mi], bh, accQ[tl][mi], 0, 0, 0);
        accQ[tl][mi] = __builtin_amdgcn_mfma_f32_16x16x32_bf16(ah[mi], bl, accQ[tl][mi], 0, 0, 0);
        accQ[tl][mi] = __builtin_amdgcn_mfma_f32_16x16x32_bf16(ah[mi], bh, accQ[tl][mi], 0, 0, 0);
      }
    }
  }

  // ---- restage A with latents (64 x 256 = 32 chunks) ----
  __syncthreads();
  {
    const int row = tid >> 2;
    const float* src0 = out + (size_t)(row0 + row)*OUT_D;
    #pragma unroll
    for (int i = 0; i < 8; ++i) {
      const int q = (tid & 3) + 4*i;  // chunk 0..31
      float4 f0 = *(const float4*)(src0 + q*8);
      float4 f1 = *(const float4*)(src0 + q*8 + 4);
      float vs[8] = {f0.x,f0.y,f0.z,f0.w,f1.x,f1.y,f1.z,f1.w};
      union { ushort u[8]; bf16x8 v; } th, tl;
      #pragma unroll
      for (int j=0;j<8;++j) split2(vs[j], th.u[j], tl.u[j]);
      *(bf16x8*)&Abuf[row*ST + q*8]      = th.v;
      *(bf16x8*)&Abuf[PL + row*ST + q*8] = tl.v;
    }
  }
  __syncthreads();

  // ---- phase K in 2 passes of 4 dh-tiles; combine in-lane + quad DPP ----
  #pragma unroll
  for (int p = 0; p < 2; ++p) {
    f32x4 accK[4][4];
    #pragma unroll
    for (int dh=0;dh<4;++dh)
      #pragma unroll
      for (int mi=0;mi<4;++mi) accK[dh][mi] = (f32x4){0.f,0.f,0.f,0.f};
    #pragma unroll
    for (int k0 = 0; k0 < 8; ++k0) {
      bf16x8 ah[4], al[4];
      #pragma unroll
      for (int mi=0;mi<4;++mi) {
        const int row = mi*16 + lr;
        ah[mi] = *(const bf16x8*)&Abuf[row*ST + k0*32 + kg*8];
        al[mi] = *(const bf16x8*)&Abuf[PL + row*ST + k0*32 + kg*8];
      }
      #pragma unroll
      for (int dh = 0; dh < 4; ++dh) {
        const size_t boff = (size_t)((wn*8 + p*4 + dh)*16 + lr)*256 + k0*32 + kg*8;
        bf16x8 bh = *(const bf16x8*)(Wkh + boff);
        bf16x8 bl = *(const bf16x8*)(Wkl + boff);
        #pragma unroll
        for (int mi=0;mi<4;++mi) {
          accK[dh][mi] = __builtin_amdgcn_mfma_f32_16x16x32_bf16(al[mi], bh, accK[dh][mi], 0, 0, 0);
          accK[dh][mi] = __builtin_amdgcn_mfma_f32_16x16x32_bf16(ah[mi], bl, accK[dh][mi], 0, 0, 0);
          accK[dh][mi] = __builtin_amdgcn_mfma_f32_16x16x32_bf16(ah[mi], bh, accK[dh][mi], 0, 0, 0);
        }
      }
    }
    // combine: att[e, m] = 4 * sum_d Q*K; m = (2wn+p)*4 + (lr>>2)
    const int m = (2*wn + p)*4 + (lr >> 2);
    #pragma unroll
    for (int mi=0;mi<4;++mi) {
      float s[4];
      #pragma unroll
      for (int r=0;r<4;++r) {
        s[r] = accQ[p*4+0][mi][r]*accK[0][mi][r]
             + accQ[p*4+1][mi][r]*accK[1][mi][r]
             + accQ[p*4+2][mi][r]*accK[2][mi][r]
             + accQ[p*4+3][mi][r]*accK[3][mi][r];
      }
      #pragma unroll
      for (int r=0;r<4;++r) {
        s[r] += __shfl_xor(s[r], 1);
        s[r] += __shfl_xor(s[r], 2);
      }
      if ((lr & 3) == 0) {
        #pragma unroll
        for (int r=0;r<4;++r) {
          const int row = row0 + mi*16 + kg*4 + r;
          att[(size_t)row*32 + m] = 4.0f * s[r];
        }
      }
    }
  }
}

// ---------------- CSR build: histogram / scan / scatter ---------------------
__global__ __launch_bounds__(256) void hist_kernel(
    const int* __restrict__ ctr, int* __restrict__ cnt)
{
  int e = blockIdx.x*256 + threadIdx.x;
  if (e < E_EDGES) atomicAdd(&cnt[ctr[e]], 1);
}

__global__ __launch_bounds__(256) void scan_kernel(
    const int* __restrict__ cnt, int* __restrict__ rowptr,
    int* __restrict__ cursor)
{
  __shared__ int part[256];
  const int t = threadIdx.x;
  const int base = t*32;
  int local[32];
  int s = 0;
  #pragma unroll
  for (int k=0;k<32;++k){ local[k]=cnt[base+k]; s+=local[k]; }
  part[t]=s; __syncthreads();
  for (int off=1; off<256; off<<=1){
    int v = (t>=off)? part[t-off] : 0;
    __syncthreads();
    part[t]+=v;
    __syncthreads();
  }
  int run = (t==0)?0:part[t-1];
  #pragma unroll
  for (int k=0;k<32;++k){ rowptr[base+k]=run; cursor[base+k]=run; run+=local[k]; }
  if (t==255) rowptr[N_NODES]=run;
}

__global__ __launch_bounds__(256) void scatter_kernel(
    const int* __restrict__ ctr, int* __restrict__ cursor,
    int* __restrict__ eidx)
{
  int e = blockIdx.x*256 + threadIdx.x;
  if (e < E_EDGES){ int p = atomicAdd(&cursor[ctr[e]],1); eidx[p]=e; }
}

// ---------------- fused per-node: softmax + env accum + so3_norm + mixing ---
__global__ __launch_bounds__(128) void node_env_kernel(
    const float* __restrict__ att, const int* __restrict__ eidx,
    const int* __restrict__ rowptr, const float* __restrict__ eattr,
    const float* __restrict__ outbuf,
    const float* __restrict__ env_nw, const float* __restrict__ env_lw,
    float* __restrict__ env2)
{
  __shared__ float mx_s[32], rs_s[32];
  __shared__ float jm[4][32], js[4][32];
  __shared__ float ev[128];
  __shared__ float2 red[128];
  const int n = blockIdx.x, t = threadIdx.x;
  const int start = rowptr[n], deg = rowptr[n+1] - start;
  {
    const int m = t & 31, j = t >> 5;
    float lm = -3.4e38f, ls = 0.f;
    for (int i = j; i < deg; i += 4) {
      float l = att[(size_t)eidx[start+i]*32 + m];
      if (l > lm) { ls = ls * __expf(lm - l) + 1.f; lm = l; }
      else ls += __expf(l - lm);
    }
    jm[j][m] = lm; js[j][m] = ls;
  }
  __syncthreads();
  if (t < 32) {
    const int m = t;
    float M = jm[0][m];
    #pragma unroll
    for (int q=1;q<4;++q) M = fmaxf(M, jm[q][m]);
    float S = 0.f;
    #pragma unroll
    for (int q=0;q<4;++q) S += js[q][m] * __expf(jm[q][m] - M);
    mx_s[m] = M;
    rs_s[m] = 1.f / (S + 1e-16f);
  }
  __syncthreads();
  const int m2 = t >> 2, d = t & 3;
  const float M2 = mx_s[m2], R2 = rs_s[m2];
  float acc = 0.f;
  for (int i = 0; i < deg; ++i) {
    const int e = eidx[start+i];
    float a = __expf(att[(size_t)e*32 + m2] - M2) * R2;
    const float* wr = outbuf + (size_t)e*OUT_D + 256;
    float w = (d==0) ? wr[64 + 2*m2] : wr[65 + 2*m2];
    float sc = wr[128 + m2];
    float ea = eattr[(size_t)e*128 + m2*4 + d];
    acc += ea * w * sc * a;
  }
  float val = acc;
  red[t] = make_float2(d==0 ? val*val : 0.f, d!=0 ? val*val : 0.f);
  __syncthreads();
  for (int off=64; off>0; off>>=1) {
    if (t<off){ red[t].x += red[t+off].x; red[t].y += red[t+off].y; }
    __syncthreads();
  }
  float inv_s = rsqrtf(red[0].x*(1.f/32.f)+EPS6);
  float inv_v = rsqrtf(red[0].y*(1.f/96.f)+EPS6);
  float nv = (d==0) ? val*inv_s*env_nw[2*m2] : val*inv_v*env_nw[2*m2+1];
  ev[t] = nv;
  __syncthreads();
  const float* WL = env_lw + (d==0 ? 0 : 1024);
  float a2 = 0.f;
  #pragma unroll 8
  for (int q=0;q<32;++q) a2 += ev[q*4+d]*WL[q*32+m2];
  env2[(size_t)n*128 + m2*4 + d] = a2;
}

// ---------------- per-edge tensor product: 32 lanes/edge, 8 edges/block -----
__global__ __launch_bounds__(256) void edge_final_kernel(
    const float* __restrict__ eq_feat, const float* __restrict__ env2,
    const int* __restrict__ ctr,
    const float* __restrict__ eq_norm_w, const float* __restrict__ tp_norm_w,
    const float* __restrict__ lin_vec_w, float* __restrict__ out)
{
  __shared__ float Wv[96*32];
  __shared__ float ov[8][96][3];
  const int tid = threadIdx.x;
  for (int i = tid; i < 96*32; i += 256) Wv[i] = lin_vec_w[i];
  __syncthreads();
  const int grp = tid >> 5;
  const int m   = tid & 31;
  const int e   = blockIdx.x*8 + grp;
  float* wrow = out + (size_t)e*OUT_D;

  float4 x   = *(const float4*)(eq_feat + ((size_t)e*32 + m)*4);
  float2 w01 = *(const float2*)(wrow + 256 + 2*m);
  float sw = x.x*w01.x, v0 = x.y*w01.y, v1 = x.z*w01.y, v2 = x.w*w01.y;
  const int nidx = ctr[e];
  float4 evv = *(const float4*)(env2 + (size_t)nidx*128 + m*4);

  float ps_ = sw*sw, pv_ = v0*v0 + v1*v1 + v2*v2;
  #pragma unroll
  for (int off=16; off; off>>=1) {
    ps_ += __shfl_xor(ps_, off, 32);
    pv_ += __shfl_xor(pv_, off, 32);
  }
  float inv_s = rsqrtf(ps_*(1.f/32.f)+EPS6);
  float inv_v = rsqrtf(pv_*(1.f/96.f)+EPS6);
  float s  = sw*inv_s*eq_norm_w[2*m];
  float fv = inv_v*eq_norm_w[2*m+1];
  v0 *= fv; v1 *= fv; v2 *= fv;
  float es = evv.x, e0 = evv.y, e1 = evv.z, e2 = evv.w;
  float os0 = s*es;
  float os1 = (v0*e0 + v1*e1 + v2*e2) * 0.5773502691896258f;
  float a00=s*e0, a01=s*e1, a02=s*e2;
  float a10=v0*es, a11=v1*es, a12=v2*es;
  const float is2 = 0.7071067811865476f;
  float a20=(v1*e2 - v2*e1)*is2;
  float a21=(v2*e0 - v0*e2)*is2;
  float a22=(v0*e1 - v1*e0)*is2;
  float q0 = os0*os0, q1 = os1*os1;
  float q2 = a00*a00+a01*a01+a02*a02;
  float q3 = a10*a10+a11*a11+a12*a12;
  float q4 = a20*a20+a21*a21+a22*a22;
  #pragma unroll
  for (int off=16; off; off>>=1) {
    q0 += __shfl_xor(q0, off, 32); q1 += __shfl_xor(q1, off, 32);
    q2 += __shfl_xor(q2, off, 32); q3 += __shfl_xor(q3, off, 32);
    q4 += __shfl_xor(q4, off, 32);
  }
  float t0 = rsqrtf(q0*(1.f/32.f)+EPS6)*tp_norm_w[m*5+0];
  float t1 = rsqrtf(q1*(1.f/32.f)+EPS6)*tp_norm_w[m*5+1];
  float f0 = rsqrtf(q2*(1.f/96.f)+EPS6)*tp_norm_w[m*5+2];
  float f1 = rsqrtf(q3*(1.f/96.f)+EPS6)*tp_norm_w[m*5+3];
  float f2 = rsqrtf(q4*(1.f/96.f)+EPS6)*tp_norm_w[m*5+4];

  *(float2*)(wrow + 256 + 2*m) = make_float2(os0*t0, os1*t1);
  ov[grp][3*m+0][0]=a00*f0; ov[grp][3*m+0][1]=a01*f0; ov[grp][3*m+0][2]=a02*f0;
  ov[grp][3*m+1][0]=a10*f1; ov[grp][3*m+1][1]=a11*f1; ov[grp][3*m+1][2]=a12*f1;
  ov[grp][3*m+2][0]=a20*f2; ov[grp][3*m+2][1]=a21*f2; ov[grp][3*m+2][2]=a22*f2;
  float acc0=0.f, acc1=0.f, acc2=0.f;
  #pragma unroll 4
  for (int i=0;i<96;++i) {
    float wv = Wv[i*32 + m];
    acc0 += ov[grp][i][0]*wv;
    acc1 += ov[grp][i][1]*wv;
    acc2 += ov[grp][i][2]*wv;
  }
  wrow[320 + 3*m + 0] = acc0;
  wrow[320 + 3*m + 1] = acc1;
  wrow[320 + 3*m + 2] = acc2;
}

// =============================================================================
extern "C" void kernel_launch(void* const* d_in, const int* in_sizes, int n_in,
                              void* d_out, int out_size, void* d_ws, size_t ws_size,
                              hipStream_t stream)
{
  (void)in_sizes; (void)n_in; (void)out_size; (void)ws_size;
  const float* x      = (const float*)d_in[0];
  const float* cut    = (const float*)d_in[1];
  const float* eqf    = (const float*)d_in[2];
  const float* eattr  = (const float*)d_in[3];
  const float* ninv   = (const float*)d_in[4];
  const float* einv   = (const float*)d_in[5];
  const float* W1     = (const float*)d_in[6];
  const float* b1     = (const float*)d_in[7];
  const float* W2     = (const float*)d_in[8];
  const float* b2     = (const float*)d_in[9];
  const float* ln_g   = (const float*)d_in[10];
  const float* ln_b   = (const float*)d_in[11];
  const float* We1    = (const float*)d_in[12];
  const float* be1    = (const float*)d_in[13];
  const float* We2    = (const float*)d_in[14];
  const float* be2    = (const float*)d_in[15];
  const float* Wq     = (const float*)d_in[16];
  const float* Wk     = (const float*)d_in[17];
  const float* eq_nw  = (const float*)d_in[18];
  const float* env_nw = (const float*)d_in[19];
  const float* env_lw = (const float*)d_in[20];
  const float* tp_nw  = (const float*)d_in[21];
  const float* lin_vw = (const float*)d_in[22];
  const int*   ctr    = (const int*)d_in[23];
  const int*   nbr    = (const int*)d_in[24];

  float* out = (float*)d_out;
  float* ws  = (float*)d_ws;
  ushort* Hhi   = (ushort*)(ws + WS_HHI);
  ushort* Hlo   = (ushort*)(ws + WS_HLO);
  float* att    = ws + WS_ATT;
  float* env2   = ws + WS_ENV2;
  int* cnt      = (int*)(ws + WS_CNT);
  int* rowptr   = (int*)(ws + WS_ROWPTR);
  int* cursor   = (int*)(ws + WS_CURSOR);
  int* eidx     = (int*)(ws + WS_EIDX);
  ushort* WB    = (ushort*)(ws + WS_WB);

  hipMemsetAsync(cnt, 0, N_NODES*sizeof(int), stream);

  // CSR build
  hist_kernel<<<E_EDGES/256, 256, 0, stream>>>(ctr, cnt);
  scan_kernel<<<1, 256, 0, stream>>>(cnt, rowptr, cursor);
  scatter_kernel<<<E_EDGES/256, 256, 0, stream>>>(ctr, cursor, eidx);

  // weight conversion (transposed, hi/lo planes; We2 zero-padded to 192 rows;
  // Wq/Wk with QK permutation)
  wconv_kernel<<<192, 256, 0, stream>>>(W1,  WB+WB_W1H,  WB+WB_W1L,  192, 256, 256);
  wconv_kernel<<<256, 256, 0, stream>>>(W2,  WB+WB_W2H,  WB+WB_W2L,  256, 256, 256);
  wconv_kernel<<<256, 256, 0, stream>>>(We1, WB+WB_WE1H, WB+WB_WE1L, 256, 256, 256);
  wconv_kernel<<<192, 256, 0, stream>>>(We2, WB+WB_WE2H, WB+WB_WE2L, 256, 160, 192);
  wconv_perm_kernel<<<384, 256, 0, stream>>>(Wq, WB+WB_WQH, WB+WB_WQL, 192);
  wconv_perm_kernel<<<512, 256, 0, stream>>>(Wk, WB+WB_WKH, WB+WB_WKL, 256);

  // G1: silu(x @ W1 + b1) -> H hi/lo
  gemm_wide<1,0,2,4,0><<<E_EDGES/128, 512, 0, stream>>>(
      x, nullptr, D_INF, WB+WB_W1H, WB+WB_W1L, 192, b1,
      Hhi, Hlo, 256, 256, nullptr, nullptr, nullptr);
  // G2: H @ W2 + b2, fused LayerNorm+cutoff -> out cols 0..255 (f32)
  gemm_wide<0,3,0,4,1><<<E_EDGES/128, 512, 0, stream>>>(
      Hhi, Hlo, 256, WB+WB_W2H, WB+WB_W2L, 256, b2,
      out, nullptr, OUT_D, 256, ln_g, ln_b, cut);
  // fused QK -> att (R9 config: 64-edge blocks, 256 threads)
  qk_att_kernel<<<E_EDGES/64, 256, 0, stream>>>(
      out, ninv, einv, ctr, nbr,
      WB+WB_WQH, WB+WB_WQL, WB+WB_WKH, WB+WB_WKL, att);
  // G3: silu(lat @ We1 + be1) -> H hi/lo (reuse)
  gemm_wide<1,0,2,4,0><<<E_EDGES/128, 512, 0, stream>>>(
      out, nullptr, OUT_D, WB+WB_WE1H, WB+WB_WE1L, 256, be1,
      Hhi, Hlo, 256, 256, nullptr, nullptr, nullptr);
  // G4: H @ We2 + be2 -> out cols 256..415 (f32, N=160, B padded to 192)
  gemm_wide<0,3,0,3,0><<<E_EDGES/128, 512, 0, stream>>>(
      Hhi, Hlo, 256, WB+WB_WE2H, WB+WB_WE2L, 256, be2,
      out + 256, nullptr, OUT_D, 160, nullptr, nullptr, nullptr);
  // fused per-node softmax + env + norm + mixing
  node_env_kernel<<<N_NODES, 128, 0, stream>>>(att, eidx, rowptr, eattr, out,
                                               env_nw, env_lw, env2);
  // final per-edge tensor product
  edge_final_kernel<<<E_EDGES/8, 256, 0, stream>>>(eqf, env2, ctr, eq_nw, tp_nw, lin_vw, out);
}

// Round 13
// 823.730 us; speedup vs baseline: 1.2400x; 1.0156x over previous
//
#include <hip/hip_runtime.h>
#include <cstddef>
#include <cstdint>

// Problem constants (fixed by setup_inputs)
#define E_EDGES 131072
#define N_NODES 8192
#define D_INF   192
#define L_DIM   256
#define OUT_D   416
#define EPS6    1e-6f
#define GA      40            // LDS row stride (shorts) for gemm_wide tiles

// ws layout (float offsets)
#define WS_HHI   0ull          // E*256 bf16 hi plane (G1/G3 out)
#define WS_HLO   16777216ull   // E*256 bf16 lo plane
#define WS_ATT   33554432ull   // E*32 f32 logits
#define WS_ENV2  37748736ull   // N*128 f32
#define WS_CNT   38797312ull   // N int
#define WS_ROWPTR 38805504ull  // N+1 int (padded)
#define WS_CURSOR 38813760ull  // N int
#define WS_EIDX  38821952ull   // E int
#define WS_WB    38953024ull   // bf16 weight planes

// WB ushort offsets (hi/lo pairs; transposed (N,K) row-major; We2 padded to 192)
#define WB_W1H   0
#define WB_W1L   49152
#define WB_W2H   98304
#define WB_W2L   163840
#define WB_WE1H  229376
#define WB_WE1L  294912
#define WB_WE2H  360448
#define WB_WE2L  409600
#define WB_WQH   458752
#define WB_WQL   557056
#define WB_WKH   655360
#define WB_WKL   786432

typedef __attribute__((ext_vector_type(8))) short bf16x8;
typedef __attribute__((ext_vector_type(4))) float f32x4;

__device__ __forceinline__ ushort f2bf(float f){
  unsigned u = __float_as_uint(f);
  unsigned r = u + 0x7fffu + ((u>>16)&1u);
  return (ushort)(r>>16);
}
__device__ __forceinline__ float bf2f(ushort h){
  return __uint_as_float(((unsigned)h)<<16);
}
__device__ __forceinline__ void split2(float v, ushort &h, ushort &l){
  h = f2bf(v);
  l = f2bf(v - bf2f(h));
}

// ---------------- weight transpose+convert: Wt[n][k] = bf16(W[k][n]) --------
// rows n >= N are zero-padded (up to Npad)
__global__ __launch_bounds__(256) void wconv_kernel(
    const float* __restrict__ W, ushort* __restrict__ Whi,
    ushort* __restrict__ Wlo, int K, int N, int Npad)
{
  int idx = blockIdx.x*256 + threadIdx.x;
  if (idx >= Npad*K) return;
  int n = idx / K, k = idx - n*K;
  float v = (n < N) ? W[(size_t)k*N + n] : 0.f;
  ushort h = f2bf(v);
  Whi[idx] = h;
  Wlo[idx] = f2bf(v - bf2f(h));
}

// QK permuted variant: output col n' = (mh*4+dh)*16 + ml*4 + dl for
// n = m*16+d, m=mh*4+ml, d=dh*4+dl. Makes the d-reduction quad-local.
__global__ __launch_bounds__(256) void wconv_perm_kernel(
    const float* __restrict__ W, ushort* __restrict__ Whi,
    ushort* __restrict__ Wlo, int K)
{
  int idx = blockIdx.x*256 + threadIdx.x;
  if (idx >= 512*K) return;
  int n = idx / K, k = idx - n*K;
  float v = W[(size_t)k*512 + n];
  int m = n >> 4, d = n & 15;
  int npr = (((m>>2)*4 + (d>>2))<<4) | ((m&3)<<2) | (d&3);
  ushort h = f2bf(v);
  Whi[(size_t)npr*K + k] = h;
  Wlo[(size_t)npr*K + k] = f2bf(v - bf2f(h));
}

// ---------------- wide split-bf16 MFMA GEMM: full-N per block, 512 thr ------
// BM=128, BN=64*WNT (4 col-stripe waves x WNT 16-col tiles), BK=32,
// 8 waves in 2x4 grid (wm: rows 0-63/64-127, wn: col stripe).
// AMODE: 0 = A f32 row-major (split on the fly), 3 = A bf16 hi/lo pair
// OMODE: 0 = f32 C, 2 = bf16 hi/lo pair C
// LNEPI: fused LayerNorm(+bias)+cutoff epilogue (G2, needs BN=256), f32 C
template<int ACT, int AMODE, int OMODE, int WNT, int LNEPI>
__global__ __launch_bounds__(512,4) void gemm_wide(
    const void* __restrict__ Aptr, const void* __restrict__ Aptr2, int lda,
    const ushort* __restrict__ Bhi, const ushort* __restrict__ Blo, int Kdim,
    const float* __restrict__ bias,
    void* __restrict__ Cptr, void* __restrict__ Cptr2, int ldc, int Ncols,
    const float* __restrict__ lng, const float* __restrict__ lnb,
    const float* __restrict__ cut)
{
  constexpr int BN = 64*WNT;
  __shared__ ushort As[2][128][GA];
  __shared__ ushort Bs[2][BN][GA];
  __shared__ float sbuf[128][4];
  __shared__ float qbuf[128][4];
  const int tid  = threadIdx.x;
  const int row0 = blockIdx.x * 128;
  const int srow = tid >> 2;          // 0..127
  const int skc  = (tid & 3) * 8;     // 0,8,16,24
  const int wid  = tid >> 6, lane = tid & 63;
  const int wm   = wid >> 2, wn = wid & 3;
  const int lr   = lane & 15, kg = lane >> 4;

  f32x4 acc[4][WNT];
  #pragma unroll
  for (int mi=0;mi<4;++mi)
    #pragma unroll
    for (int ni=0;ni<WNT;++ni) acc[mi][ni] = (f32x4){0.f,0.f,0.f,0.f};

  for (int k0 = 0; k0 < Kdim; k0 += 32) {
    for (int br = srow; br < BN; br += 128) {
      *(bf16x8*)&Bs[0][br][skc] = *(const bf16x8*)(Bhi + (size_t)br*Kdim + k0 + skc);
      *(bf16x8*)&Bs[1][br][skc] = *(const bf16x8*)(Blo + (size_t)br*Kdim + k0 + skc);
    }
    {
      const int row = srow;
      if (AMODE == 3) {
        const size_t off = (size_t)(row0+row)*lda + k0 + skc;
        *(bf16x8*)&As[0][row][skc] = *(const bf16x8*)((const ushort*)Aptr + off);
        *(bf16x8*)&As[1][row][skc] = *(const bf16x8*)((const ushort*)Aptr2 + off);
      } else {
        const float* ap = (const float*)Aptr + (size_t)(row0+row)*lda + k0 + skc;
        float4 f0 = *(const float4*)ap;
        float4 f1 = *(const float4*)(ap+4);
        float vs[8] = {f0.x,f0.y,f0.z,f0.w,f1.x,f1.y,f1.z,f1.w};
        union { ushort u[8]; bf16x8 v; } th, tl;
        #pragma unroll
        for (int j=0;j<8;++j) split2(vs[j], th.u[j], tl.u[j]);
        *(bf16x8*)&As[0][row][skc] = th.v;
        *(bf16x8*)&As[1][row][skc] = tl.v;
      }
    }
    __syncthreads();
    bf16x8 ah[4], al[4];
    #pragma unroll
    for (int mi=0;mi<4;++mi) {
      ah[mi] = *(const bf16x8*)&As[0][wm*64 + mi*16 + lr][kg*8];
      al[mi] = *(const bf16x8*)&As[1][wm*64 + mi*16 + lr][kg*8];
    }
    #pragma unroll
    for (int ni=0;ni<WNT;++ni) {
      const int bro = wn*(16*WNT) + ni*16 + lr;
      bf16x8 bh = *(const bf16x8*)&Bs[0][bro][kg*8];
      bf16x8 bl = *(const bf16x8*)&Bs[1][bro][kg*8];
      #pragma unroll
      for (int mi=0;mi<4;++mi) {
        acc[mi][ni] = __builtin_amdgcn_mfma_f32_16x16x32_bf16(al[mi], bh, acc[mi][ni], 0, 0, 0);
        acc[mi][ni] = __builtin_amdgcn_mfma_f32_16x16x32_bf16(ah[mi], bl, acc[mi][ni], 0, 0, 0);
        acc[mi][ni] = __builtin_amdgcn_mfma_f32_16x16x32_bf16(ah[mi], bh, acc[mi][ni], 0, 0, 0);
      }
    }
    __syncthreads();
  }

  if (!LNEPI) {
    #pragma unroll
    for (int ni=0;ni<WNT;++ni) {
      const int col = wn*(16*WNT) + ni*16 + lr;
      const float bv = (col < Ncols) ? bias[col] : 0.f;
      #pragma unroll
      for (int mi=0;mi<4;++mi) {
        #pragma unroll
        for (int r=0;r<4;++r) {
          const int row = row0 + wm*64 + mi*16 + kg*4 + r;
          float v = acc[mi][ni][r] + bv;
          if (ACT == 1) v = v / (1.f + __expf(-v));
          const size_t oidx = (size_t)row*ldc + col;
          if (col < Ncols) {
            if (OMODE == 0) ((float*)Cptr)[oidx] = v;
            else {
              ushort h, l; split2(v, h, l);
              ((ushort*)Cptr)[oidx]  = h;
              ((ushort*)Cptr2)[oidx] = l;
            }
          }
        }
      }
    }
  } else {
    // fused bias + LayerNorm + cutoff epilogue (BN=256 covers full row)
    float bsv[WNT], gvv[WNT], bvv[WNT];
    #pragma unroll
    for (int ni=0;ni<WNT;++ni) {
      const int col = wn*(16*WNT) + ni*16 + lr;
      bsv[ni] = bias[col]; gvv[ni] = lng[col]; bvv[ni] = lnb[col];
    }
    #pragma unroll
    for (int mi=0;mi<4;++mi) {
      #pragma unroll
      for (int r=0;r<4;++r) {
        float s = 0.f, q = 0.f;
        #pragma unroll
        for (int ni=0;ni<WNT;++ni) {
          float v = acc[mi][ni][r] + bsv[ni];
          acc[mi][ni][r] = v;
          s += v; q += v*v;
        }
        s += __shfl_xor(s, 1); q += __shfl_xor(q, 1);
        s += __shfl_xor(s, 2); q += __shfl_xor(q, 2);
        s += __shfl_xor(s, 4); q += __shfl_xor(q, 4);
        s += __shfl_xor(s, 8); q += __shfl_xor(q, 8);
        if (lr == 0) {
          const int rl = wm*64 + mi*16 + kg*4 + r;
          sbuf[rl][wn] = s; qbuf[rl][wn] = q;
        }
      }
    }
    __syncthreads();
    #pragma unroll
    for (int mi=0;mi<4;++mi) {
      #pragma unroll
      for (int r=0;r<4;++r) {
        const int rl = wm*64 + mi*16 + kg*4 + r;
        const float S = sbuf[rl][0] + sbuf[rl][1] + sbuf[rl][2] + sbuf[rl][3];
        const float Q = qbuf[rl][0] + qbuf[rl][1] + qbuf[rl][2] + qbuf[rl][3];
        const float mean = S * (1.f/256.f);
        const float var  = Q * (1.f/256.f) - mean*mean;
        const float rs   = rsqrtf(var + 1e-5f);
        const float cutv = cut[row0 + rl];
        #pragma unroll
        for (int ni=0;ni<WNT;++ni) {
          const int col = wn*(16*WNT) + ni*16 + lr;
          float nv = (acc[mi][ni][r] - mean)*rs*gvv[ni] + bvv[ni];
          if (col < 128) nv *= cutv;
          ((float*)Cptr)[(size_t)(row0 + rl)*ldc + col] = nv;
        }
      }
    }
  }
}

// ---------------- fused QK attention logits (n-split, deep-prefetch) --------
// Grid (E/64, 2): 64 edges x 256 permuted cols (16 tiles; 4 per wave).
// blockIdx.y = column half h; wave wn owns tiles h*16 + wn*4 + tl (tl=dh,
// mh = h*4+wn). accQ[4][4] + accK[4][4] = 128 VGPR accumulators; budget is
// 256 (LDS caps occupancy at 2 blocks/CU), so all 8 B-pairs per k0 batch-
// prefetch into registers. A staged once in LDS (padded stride 264).
// d-reduction: in-lane over tl + quad shfl_xor(1,2).
__global__ __launch_bounds__(256,2) void qk_att_kernel(
    const float* __restrict__ out, const float* __restrict__ ninv,
    const float* __restrict__ einv,
    const int* __restrict__ ctr, const int* __restrict__ nbr,
    const ushort* __restrict__ Wqh, const ushort* __restrict__ Wql,
    const ushort* __restrict__ Wkh, const ushort* __restrict__ Wkl,
    float* __restrict__ att)
{
  constexpr int ST = 264;            // padded row stride (ushorts)
  constexpr int PL = 64*ST;          // lo-plane offset
  __shared__ ushort Abuf[2*64*ST];   // 67.6 KB
  const int tid  = threadIdx.x;
  const int row0 = blockIdx.x * 64;
  const int h    = blockIdx.y;       // column half (tiles h*16..h*16+15)
  const int wn   = tid >> 6;
  const int lane = tid & 63;
  const int lr   = lane & 15, kg = lane >> 4;

  // ---- stage efa (64 x 192 = 24 chunks of 8) hi/lo once ----
  {
    const int row = tid >> 2;         // 0..63
    const int ge  = row0 + row;
    const int ci  = ctr[ge], nn = nbr[ge];
    #pragma unroll
    for (int i = 0; i < 6; ++i) {
      const int q = (tid & 3) + 4*i;  // chunk 0..23 (k = q*8)
      const float* src;
      if (q < 8)       src = ninv + (size_t)ci*64 + q*8;
      else if (q < 16) src = ninv + (size_t)nn*64 + (q-8)*8;
      else             src = einv + (size_t)ge*64 + (q-16)*8;
      float4 f0 = *(const float4*)src;
      float4 f1 = *(const float4*)(src+4);
      float vs[8] = {f0.x,f0.y,f0.z,f0.w,f1.x,f1.y,f1.z,f1.w};
      union { ushort u[8]; bf16x8 v; } th, tl;
      #pragma unroll
      for (int j=0;j<8;++j) split2(vs[j], th.u[j], tl.u[j]);
      *(bf16x8*)&Abuf[row*ST + q*8]      = th.v;
      *(bf16x8*)&Abuf[PL + row*ST + q*8] = tl.v;
    }
  }
  __syncthreads();

  // ---- phase Q: accQ[4 tiles][4 mi], k0-outer, batch B prefetch ----
  f32x4 accQ[4][4];
  #pragma unroll
  for (int t=0;t<4;++t)
    #pragma unroll
    for (int mi=0;mi<4;++mi) accQ[t][mi] = (f32x4){0.f,0.f,0.f,0.f};

  #pragma unroll
  for (int k0 = 0; k0 < 6; ++k0) {
    // batch-load all 8 B pairs for this k0 (independent -> deep in flight)
    bf16x8 bqh[4], bql[4];
    #pragma unroll
    for (int tl = 0; tl < 4; ++tl) {
      const size_t boff = (size_t)((h*16 + wn*4 + tl)*16 + lr)*192 + k0*32 + kg*8;
      bqh[tl] = *(const bf16x8*)(Wqh + boff);
      bql[tl] = *(const bf16x8*)(Wql + boff);
    }
    bf16x8 ah[4], al[4];
    #pragma unroll
    for (int mi=0;mi<4;++mi) {
      const int row = mi*16 + lr;
      ah[mi] = *(const bf16x8*)&Abuf[row*ST + k0*32 + kg*8];
      al[mi] = *(const bf16x8*)&Abuf[PL + row*ST + k0*32 + kg*8];
    }
    __builtin_amdgcn_s_setprio(1);
    #pragma unroll
    for (int tl = 0; tl < 4; ++tl)
      #pragma unroll
      for (int mi=0;mi<4;++mi) {
        accQ[tl][mi] = __builtin_amdgcn_mfma_f32_16x16x32_bf16(al[mi], bqh[tl], accQ[tl][mi], 0, 0, 0);
        accQ[tl][mi] = __builtin_amdgcn_mfma_f32_16x16x32_bf16(ah[mi], bql[tl], accQ[tl][mi], 0, 0, 0);
        accQ[tl][mi] = __builtin_amdgcn_mfma_f32_16x16x32_bf16(ah[mi], bqh[tl], accQ[tl][mi], 0, 0, 0);
      }
    __builtin_amdgcn_s_setprio(0);
  }

  // ---- restage A with latents (64 x 256 = 32 chunks) ----
  __syncthreads();
  {
    const int row = tid >> 2;
    const float* src0 = out + (size_t)(row0 + row)*OUT_D;
    #pragma unroll
    for (int i = 0; i < 8; ++i) {
      const int q = (tid & 3) + 4*i;  // chunk 0..31
      float4 f0 = *(const float4*)(src0 + q*8);
      float4 f1 = *(const float4*)(src0 + q*8 + 4);
      float vs[8] = {f0.x,f0.y,f0.z,f0.w,f1.x,f1.y,f1.z,f1.w};
      union { ushort u[8]; bf16x8 v; } th, tl;
      #pragma unroll
      for (int j=0;j<8;++j) split2(vs[j], th.u[j], tl.u[j]);
      *(bf16x8*)&Abuf[row*ST + q*8]      = th.v;
      *(bf16x8*)&Abuf[PL + row*ST + q*8] = tl.v;
    }
  }
  __syncthreads();

  // ---- phase K: accK[4 tiles][4 mi], k0-outer, batch B prefetch ----
  f32x4 accK[4][4];
  #pragma unroll
  for (int t=0;t<4;++t)
    #pragma unroll
    for (int mi=0;mi<4;++mi) accK[t][mi] = (f32x4){0.f,0.f,0.f,0.f};

  #pragma unroll
  for (int k0 = 0; k0 < 8; ++k0) {
    bf16x8 bkh[4], bkl[4];
    #pragma unroll
    for (int tl = 0; tl < 4; ++tl) {
      const size_t boff = (size_t)((h*16 + wn*4 + tl)*16 + lr)*256 + k0*32 + kg*8;
      bkh[tl] = *(const bf16x8*)(Wkh + boff);
      bkl[tl] = *(const bf16x8*)(Wkl + boff);
    }
    bf16x8 ah[4], al[4];
    #pragma unroll
    for (int mi=0;mi<4;++mi) {
      const int row = mi*16 + lr;
      ah[mi] = *(const bf16x8*)&Abuf[row*ST + k0*32 + kg*8];
      al[mi] = *(const bf16x8*)&Abuf[PL + row*ST + k0*32 + kg*8];
    }
    __builtin_amdgcn_s_setprio(1);
    #pragma unroll
    for (int tl = 0; tl < 4; ++tl)
      #pragma unroll
      for (int mi=0;mi<4;++mi) {
        accK[tl][mi] = __builtin_amdgcn_mfma_f32_16x16x32_bf16(al[mi], bkh[tl], accK[tl][mi], 0, 0, 0);
        accK[tl][mi] = __builtin_amdgcn_mfma_f32_16x16x32_bf16(ah[mi], bkl[tl], accK[tl][mi], 0, 0, 0);
        accK[tl][mi] = __builtin_amdgcn_mfma_f32_16x16x32_bf16(ah[mi], bkh[tl], accK[tl][mi], 0, 0, 0);
      }
    __builtin_amdgcn_s_setprio(0);
  }

  // ---- combine: att[e, m] = 4 * sum_d Q*K; m = (h*4+wn)*4 + (lr>>2) ----
  const int m = (h*4 + wn)*4 + (lr >> 2);
  #pragma unroll
  for (int mi=0;mi<4;++mi) {
    f32x4 sv = accQ[0][mi]*accK[0][mi] + accQ[1][mi]*accK[1][mi]
             + accQ[2][mi]*accK[2][mi] + accQ[3][mi]*accK[3][mi];
    float s[4] = {sv[0], sv[1], sv[2], sv[3]};
    #pragma unroll
    for (int r=0;r<4;++r) {
      s[r] += __shfl_xor(s[r], 1);
      s[r] += __shfl_xor(s[r], 2);
    }
    if ((lr & 3) == 0) {
      #pragma unroll
      for (int r=0;r<4;++r) {
        const int row = row0 + mi*16 + kg*4 + r;
        att[(size_t)row*32 + m] = 4.0f * s[r];
      }
    }
  }
}

// ---------------- CSR build: histogram / scan / scatter ---------------------
__global__ __launch_bounds__(256) void hist_kernel(
    const int* __restrict__ ctr, int* __restrict__ cnt)
{
  int e = blockIdx.x*256 + threadIdx.x;
  if (e < E_EDGES) atomicAdd(&cnt[ctr[e]], 1);
}

__global__ __launch_bounds__(256) void scan_kernel(
    const int* __restrict__ cnt, int* __restrict__ rowptr,
    int* __restrict__ cursor)
{
  __shared__ int part[256];
  const int t = threadIdx.x;
  const int base = t*32;
  int local[32];
  int s = 0;
  #pragma unroll
  for (int k=0;k<32;++k){ local[k]=cnt[base+k]; s+=local[k]; }
  part[t]=s; __syncthreads();
  for (int off=1; off<256; off<<=1){
    int v = (t>=off)? part[t-off] : 0;
    __syncthreads();
    part[t]+=v;
    __syncthreads();
  }
  int run = (t==0)?0:part[t-1];
  #pragma unroll
  for (int k=0;k<32;++k){ rowptr[base+k]=run; cursor[base+k]=run; run+=local[k]; }
  if (t==255) rowptr[N_NODES]=run;
}

__global__ __launch_bounds__(256) void scatter_kernel(
    const int* __restrict__ ctr, int* __restrict__ cursor,
    int* __restrict__ eidx)
{
  int e = blockIdx.x*256 + threadIdx.x;
  if (e < E_EDGES){ int p = atomicAdd(&cursor[ctr[e]],1); eidx[p]=e; }
}

// ---------------- fused per-node: softmax + env accum + so3_norm + mixing ---
__global__ __launch_bounds__(128) void node_env_kernel(
    const float* __restrict__ att, const int* __restrict__ eidx,
    const int* __restrict__ rowptr, const float* __restrict__ eattr,
    const float* __restrict__ outbuf,
    const float* __restrict__ env_nw, const float* __restrict__ env_lw,
    float* __restrict__ env2)
{
  __shared__ float mx_s[32], rs_s[32];
  __shared__ float jm[4][32], js[4][32];
  __shared__ float ev[128];
  __shared__ float2 red[128];
  const int n = blockIdx.x, t = threadIdx.x;
  const int start = rowptr[n], deg = rowptr[n+1] - start;
  {
    const int m = t & 31, j = t >> 5;
    float lm = -3.4e38f, ls = 0.f;
    for (int i = j; i < deg; i += 4) {
      float l = att[(size_t)eidx[start+i]*32 + m];
      if (l > lm) { ls = ls * __expf(lm - l) + 1.f; lm = l; }
      else ls += __expf(l - lm);
    }
    jm[j][m] = lm; js[j][m] = ls;
  }
  __syncthreads();
  if (t < 32) {
    const int m = t;
    float M = jm[0][m];
    #pragma unroll
    for (int q=1;q<4;++q) M = fmaxf(M, jm[q][m]);
    float S = 0.f;
    #pragma unroll
    for (int q=0;q<4;++q) S += js[q][m] * __expf(jm[q][m] - M);
    mx_s[m] = M;
    rs_s[m] = 1.f / (S + 1e-16f);
  }
  __syncthreads();
  const int m2 = t >> 2, d = t & 3;
  const float M2 = mx_s[m2], R2 = rs_s[m2];
  float acc = 0.f;
  for (int i = 0; i < deg; ++i) {
    const int e = eidx[start+i];
    float a = __expf(att[(size_t)e*32 + m2] - M2) * R2;
    const float* wr = outbuf + (size_t)e*OUT_D + 256;
    float w = (d==0) ? wr[64 + 2*m2] : wr[65 + 2*m2];
    float sc = wr[128 + m2];
    float ea = eattr[(size_t)e*128 + m2*4 + d];
    acc += ea * w * sc * a;
  }
  float val = acc;
  red[t] = make_float2(d==0 ? val*val : 0.f, d!=0 ? val*val : 0.f);
  __syncthreads();
  for (int off=64; off>0; off>>=1) {
    if (t<off){ red[t].x += red[t+off].x; red[t].y += red[t+off].y; }
    __syncthreads();
  }
  float inv_s = rsqrtf(red[0].x*(1.f/32.f)+EPS6);
  float inv_v = rsqrtf(red[0].y*(1.f/96.f)+EPS6);
  float nv = (d==0) ? val*inv_s*env_nw[2*m2] : val*inv_v*env_nw[2*m2+1];
  ev[t] = nv;
  __syncthreads();
  const float* WL = env_lw + (d==0 ? 0 : 1024);
  float a2 = 0.f;
  #pragma unroll 8
  for (int q=0;q<32;++q) a2 += ev[q*4+d]*WL[q*32+m2];
  env2[(size_t)n*128 + m2*4 + d] = a2;
}

// ---------------- per-edge tensor product: 32 lanes/edge, 8 edges/block -----
__global__ __launch_bounds__(256) void edge_final_kernel(
    const float* __restrict__ eq_feat, const float* __restrict__ env2,
    const int* __restrict__ ctr,
    const float* __restrict__ eq_norm_w, const float* __restrict__ tp_norm_w,
    const float* __restrict__ lin_vec_w, float* __restrict__ out)
{
  __shared__ float Wv[96*32];
  __shared__ float ov[8][96][3];
  const int tid = threadIdx.x;
  for (int i = tid; i < 96*32; i += 256) Wv[i] = lin_vec_w[i];
  __syncthreads();
  const int grp = tid >> 5;
  const int m   = tid & 31;
  const int e   = blockIdx.x*8 + grp;
  float* wrow = out + (size_t)e*OUT_D;

  float4 x   = *(const float4*)(eq_feat + ((size_t)e*32 + m)*4);
  float2 w01 = *(const float2*)(wrow + 256 + 2*m);
  float sw = x.x*w01.x, v0 = x.y*w01.y, v1 = x.z*w01.y, v2 = x.w*w01.y;
  const int nidx = ctr[e];
  float4 evv = *(const float4*)(env2 + (size_t)nidx*128 + m*4);

  float ps_ = sw*sw, pv_ = v0*v0 + v1*v1 + v2*v2;
  #pragma unroll
  for (int off=16; off; off>>=1) {
    ps_ += __shfl_xor(ps_, off, 32);
    pv_ += __shfl_xor(pv_, off, 32);
  }
  float inv_s = rsqrtf(ps_*(1.f/32.f)+EPS6);
  float inv_v = rsqrtf(pv_*(1.f/96.f)+EPS6);
  float s  = sw*inv_s*eq_norm_w[2*m];
  float fv = inv_v*eq_norm_w[2*m+1];
  v0 *= fv; v1 *= fv; v2 *= fv;
  float es = evv.x, e0 = evv.y, e1 = evv.z, e2 = evv.w;
  float os0 = s*es;
  float os1 = (v0*e0 + v1*e1 + v2*e2) * 0.5773502691896258f;
  float a00=s*e0, a01=s*e1, a02=s*e2;
  float a10=v0*es, a11=v1*es, a12=v2*es;
  const float is2 = 0.7071067811865476f;
  float a20=(v1*e2 - v2*e1)*is2;
  float a21=(v2*e0 - v0*e2)*is2;
  float a22=(v0*e1 - v1*e0)*is2;
  float q0 = os0*os0, q1 = os1*os1;
  float q2 = a00*a00+a01*a01+a02*a02;
  float q3 = a10*a10+a11*a11+a12*a12;
  float q4 = a20*a20+a21*a21+a22*a22;
  #pragma unroll
  for (int off=16; off; off>>=1) {
    q0 += __shfl_xor(q0, off, 32); q1 += __shfl_xor(q1, off, 32);
    q2 += __shfl_xor(q2, off, 32); q3 += __shfl_xor(q3, off, 32);
    q4 += __shfl_xor(q4, off, 32);
  }
  float t0 = rsqrtf(q0*(1.f/32.f)+EPS6)*tp_norm_w[m*5+0];
  float t1 = rsqrtf(q1*(1.f/32.f)+EPS6)*tp_norm_w[m*5+1];
  float f0 = rsqrtf(q2*(1.f/96.f)+EPS6)*tp_norm_w[m*5+2];
  float f1 = rsqrtf(q3*(1.f/96.f)+EPS6)*tp_norm_w[m*5+3];
  float f2 = rsqrtf(q4*(1.f/96.f)+EPS6)*tp_norm_w[m*5+4];

  *(float2*)(wrow + 256 + 2*m) = make_float2(os0*t0, os1*t1);
  ov[grp][3*m+0][0]=a00*f0; ov[grp][3*m+0][1]=a01*f0; ov[grp][3*m+0][2]=a02*f0;
  ov[grp][3*m+1][0]=a10*f1; ov[grp][3*m+1][1]=a11*f1; ov[grp][3*m+1][2]=a12*f1;
  ov[grp][3*m+2][0]=a20*f2; ov[grp][3*m+2][1]=a21*f2; ov[grp][3*m+2][2]=a22*f2;
  float acc0=0.f, acc1=0.f, acc2=0.f;
  #pragma unroll 4
  for (int i=0;i<96;++i) {
    float wv = Wv[i*32 + m];
    acc0 += ov[grp][i][0]*wv;
    acc1 += ov[grp][i][1]*wv;
    acc2 += ov[grp][i][2]*wv;
  }
  wrow[320 + 3*m + 0] = acc0;
  wrow[320 + 3*m + 1] = acc1;
  wrow[320 + 3*m + 2] = acc2;
}

// =============================================================================
extern "C" void kernel_launch(void* const* d_in, const int* in_sizes, int n_in,
                              void* d_out, int out_size, void* d_ws, size_t ws_size,
                              hipStream_t stream)
{
  (void)in_sizes; (void)n_in; (void)out_size; (void)ws_size;
  const float* x      = (const float*)d_in[0];
  const float* cut    = (const float*)d_in[1];
  const float* eqf    = (const float*)d_in[2];
  const float* eattr  = (const float*)d_in[3];
  const float* ninv   = (const float*)d_in[4];
  const float* einv   = (const float*)d_in[5];
  const float* W1     = (const float*)d_in[6];
  const float* b1     = (const float*)d_in[7];
  const float* W2     = (const float*)d_in[8];
  const float* b2     = (const float*)d_in[9];
  const float* ln_g   = (const float*)d_in[10];
  const float* ln_b   = (const float*)d_in[11];
  const float* We1    = (const float*)d_in[12];
  const float* be1    = (const float*)d_in[13];
  const float* We2    = (const float*)d_in[14];
  const float* be2    = (const float*)d_in[15];
  const float* Wq     = (const float*)d_in[16];
  const float* Wk     = (const float*)d_in[17];
  const float* eq_nw  = (const float*)d_in[18];
  const float* env_nw = (const float*)d_in[19];
  const float* env_lw = (const float*)d_in[20];
  const float* tp_nw  = (const float*)d_in[21];
  const float* lin_vw = (const float*)d_in[22];
  const int*   ctr    = (const int*)d_in[23];
  const int*   nbr    = (const int*)d_in[24];

  float* out = (float*)d_out;
  float* ws  = (float*)d_ws;
  ushort* Hhi   = (ushort*)(ws + WS_HHI);
  ushort* Hlo   = (ushort*)(ws + WS_HLO);
  float* att    = ws + WS_ATT;
  float* env2   = ws + WS_ENV2;
  int* cnt      = (int*)(ws + WS_CNT);
  int* rowptr   = (int*)(ws + WS_ROWPTR);
  int* cursor   = (int*)(ws + WS_CURSOR);
  int* eidx     = (int*)(ws + WS_EIDX);
  ushort* WB    = (ushort*)(ws + WS_WB);

  hipMemsetAsync(cnt, 0, N_NODES*sizeof(int), stream);

  // CSR build
  hist_kernel<<<E_EDGES/256, 256, 0, stream>>>(ctr, cnt);
  scan_kernel<<<1, 256, 0, stream>>>(cnt, rowptr, cursor);
  scatter_kernel<<<E_EDGES/256, 256, 0, stream>>>(ctr, cursor, eidx);

  // weight conversion (transposed, hi/lo planes; We2 zero-padded to 192 rows;
  // Wq/Wk with QK permutation)
  wconv_kernel<<<192, 256, 0, stream>>>(W1,  WB+WB_W1H,  WB+WB_W1L,  192, 256, 256);
  wconv_kernel<<<256, 256, 0, stream>>>(W2,  WB+WB_W2H,  WB+WB_W2L,  256, 256, 256);
  wconv_kernel<<<256, 256, 0, stream>>>(We1, WB+WB_WE1H, WB+WB_WE1L, 256, 256, 256);
  wconv_kernel<<<192, 256, 0, stream>>>(We2, WB+WB_WE2H, WB+WB_WE2L, 256, 160, 192);
  wconv_perm_kernel<<<384, 256, 0, stream>>>(Wq, WB+WB_WQH, WB+WB_WQL, 192);
  wconv_perm_kernel<<<512, 256, 0, stream>>>(Wk, WB+WB_WKH, WB+WB_WKL, 256);

  // G1: silu(x @ W1 + b1) -> H hi/lo
  gemm_wide<1,0,2,4,0><<<E_EDGES/128, 512, 0, stream>>>(
      x, nullptr, D_INF, WB+WB_W1H, WB+WB_W1L, 192, b1,
      Hhi, Hlo, 256, 256, nullptr, nullptr, nullptr);
  // G2: H @ W2 + b2, fused LayerNorm+cutoff -> out cols 0..255 (f32)
  gemm_wide<0,3,0,4,1><<<E_EDGES/128, 512, 0, stream>>>(
      Hhi, Hlo, 256, WB+WB_W2H, WB+WB_W2L, 256, b2,
      out, nullptr, OUT_D, 256, ln_g, ln_b, cut);
  // fused QK -> att (64 edges x column-half, deep B prefetch)
  qk_att_kernel<<<dim3(E_EDGES/64, 2), 256, 0, stream>>>(
      out, ninv, einv, ctr, nbr,
      WB+WB_WQH, WB+WB_WQL, WB+WB_WKH, WB+WB_WKL, att);
  // G3: silu(lat @ We1 + be1) -> H hi/lo (reuse)
  gemm_wide<1,0,2,4,0><<<E_EDGES/128, 512, 0, stream>>>(
      out, nullptr, OUT_D, WB+WB_WE1H, WB+WB_WE1L, 256, be1,
      Hhi, Hlo, 256, 256, nullptr, nullptr, nullptr);
  // G4: H @ We2 + be2 -> out cols 256..415 (f32, N=160, B padded to 192)
  gemm_wide<0,3,0,3,0><<<E_EDGES/128, 512, 0, stream>>>(
      Hhi, Hlo, 256, WB+WB_WE2H, WB+WB_WE2L, 256, be2,
      out + 256, nullptr, OUT_D, 160, nullptr, nullptr, nullptr);
  // fused per-node softmax + env + norm + mixing
  node_env_kernel<<<N_NODES, 128, 0, stream>>>(att, eidx, rowptr, eattr, out,
                                               env_nw, env_lw, env2);
  // final per-edge tensor product
  edge_final_kernel<<<E_EDGES/8, 256, 0, stream>>>(eqf, env2, ctr, eq_nw, tp_nw, lin_vw, out);
}